// Round 6
// baseline (772.904 us; speedup 1.0000x reference)
//
#include <hip/hip_runtime.h>
#include <hip/hip_bf16.h>
#include <stdint.h>

typedef __attribute__((ext_vector_type(8))) short short8;
typedef __attribute__((ext_vector_type(4))) float f32x4;
typedef unsigned short u16;

#define BATCH 4
#define NH    16
#define SEQ   2048
#define DM    1024
#define HD    64

__device__ __forceinline__ u16 f32_to_f16(float f) {
    _Float16 h = (_Float16)f;
    return __builtin_bit_cast(unsigned short, h);
}
__device__ __forceinline__ float f16_to_f32(u16 u) {
    _Float16 h = __builtin_bit_cast(_Float16, u);
    return (float)h;
}

__device__ __forceinline__ void gload_lds16(const void* g, void* l) {
    __builtin_amdgcn_global_load_lds(
        (const __attribute__((address_space(1))) void*)g,
        (__attribute__((address_space(3))) void*)l, 16, 0, 0);
}

// ---------------- K0a: convert x to fp16 ----------------
__global__ void k_split_x(const float4* __restrict__ x, ushort4* __restrict__ xf, int n4) {
    int i = blockIdx.x * 256 + threadIdx.x;
    if (i >= n4) return;
    float4 v = x[i];
    float f[4] = {v.x, v.y, v.z, v.w};
    ushort4 h;
    u16* hp = (u16*)&h;
#pragma unroll
    for (int j = 0; j < 4; j++) hp[j] = f32_to_f16(f[j]);
    xf[i] = h;
}

// ---------------- K0b: transpose + convert the 4 weight matrices to fp16 ----------------
__global__ void k_split_w(const float* __restrict__ w0, const float* __restrict__ w1,
                          const float* __restrict__ w2, const float* __restrict__ w3,
                          u16* __restrict__ wt) {
    __shared__ float tile[32][33];
    int bx = blockIdx.x;
    int wi = bx >> 10;
    int t  = bx & 1023;
    int kt = t >> 5, nt = t & 31;
    const float* w = (wi == 0) ? w0 : (wi == 1) ? w1 : (wi == 2) ? w2 : w3;
    int tx = threadIdx.x & 31, ty = threadIdx.x >> 5;
#pragma unroll
    for (int i = 0; i < 4; i++) {
        int r = ty + i * 8;
        tile[r][tx] = w[(size_t)(kt * 32 + r) * 1024 + nt * 32 + tx];
    }
    __syncthreads();
    size_t base = ((size_t)wi << 20);
#pragma unroll
    for (int i = 0; i < 4; i++) {
        int r = ty + i * 8;
        size_t dst = base + (size_t)(nt * 32 + r) * 1024 + kt * 32 + tx;
        wt[dst] = f32_to_f16(tile[tx][r]);
    }
}

// ================= m97-style 128x128 GEMM core (unchanged from R5) =================
#define GEMM_KLOOP(Aptr, Bptr, am0, bn0)                                              \
    f32x4 acc[4][4];                                                                   \
    _Pragma("unroll")                                                                  \
    for (int mt = 0; mt < 4; mt++)                                                     \
        _Pragma("unroll")                                                              \
        for (int nt = 0; nt < 4; nt++) acc[mt][nt] = (f32x4)0.f;                       \
    int rowc = lane >> 3;                                                              \
    int slx  = (lane & 7) ^ rowc;   /* pre-swizzled source slot */                     \
    int kx   = slx << 3;                                                               \
    for (int k0 = 0; k0 < 1024; k0 += 64) {                                            \
        _Pragma("unroll")                                                              \
        for (int i = 0; i < 4; i++) {                                                  \
            int c = w * 4 + i;                                                         \
            int row = c * 8 + rowc;                                                    \
            gload_lds16(Aptr + (size_t)(am0 + row) * 1024 + k0 + kx,                   \
                        (char*)As + c * 1024 + lane * 16);                             \
            gload_lds16(Bptr + (size_t)(bn0 + row) * 1024 + k0 + kx,                   \
                        (char*)Bs + c * 1024 + lane * 16);                             \
        }                                                                              \
        __syncthreads();                                                               \
        _Pragma("unroll")                                                              \
        for (int kk = 0; kk < 2; kk++) {                                               \
            short8 af[4], bf[4];                                                       \
            _Pragma("unroll")                                                          \
            for (int mt = 0; mt < 4; mt++) {                                           \
                int row = wr * 64 + mt * 16 + lrow;                                    \
                int slot = (kk * 4 + (lane >> 4)) ^ (row & 7);                         \
                af[mt] = *(const short8*)(As + row * 64 + slot * 8);                   \
            }                                                                          \
            _Pragma("unroll")                                                          \
            for (int nt = 0; nt < 4; nt++) {                                           \
                int row = wc * 64 + nt * 16 + lrow;                                    \
                int slot = (kk * 4 + (lane >> 4)) ^ (row & 7);                         \
                bf[nt] = *(const short8*)(Bs + row * 64 + slot * 8);                   \
            }                                                                          \
            _Pragma("unroll")                                                          \
            for (int mt = 0; mt < 4; mt++)                                             \
                _Pragma("unroll")                                                      \
                for (int nt = 0; nt < 4; nt++)                                         \
                    acc[mt][nt] = __builtin_amdgcn_mfma_f32_16x16x32_f16(              \
                        af[mt], bf[nt], acc[mt][nt], 0, 0, 0);                         \
        }                                                                              \
        __syncthreads();                                                               \
    }

// ---------------- K1: QKV projection GEMM ----------------
__global__ __launch_bounds__(256) void k_gemm_qkv(
    const u16* __restrict__ xf, const u16* __restrict__ wt,
    const float* __restrict__ bq, const float* __restrict__ bk, const float* __restrict__ bv,
    u16* __restrict__ qf, u16* __restrict__ kf, u16* __restrict__ vt) {
    __shared__ u16 As[128 * 64];
    __shared__ u16 Bs[128 * 64];
    int lane = threadIdx.x & 63, w = threadIdx.x >> 6;
    int wr = w >> 1, wc = w & 1;
    int lrow = lane & 15, rbase = (lane >> 4) * 4;
    int lin = blockIdx.y * 24 + blockIdx.x;
    int lin2 = (lin & 7) * 192 + (lin >> 3);
    int bx = lin2 % 24, by = lin2 / 24;
    int am0 = by * 128;
    int n0 = bx * 128;
    int wi = n0 >> 10;
    int nn0 = n0 & 1023;
    const u16* bmat = wt + ((size_t)wi << 20);

    GEMM_KLOOP(xf, bmat, am0, nn0)

    const float* bias = (wi == 0) ? bq : (wi == 1) ? bk : bv;
#pragma unroll
    for (int mt = 0; mt < 4; mt++)
#pragma unroll
        for (int nt = 0; nt < 4; nt++) {
            int n = nn0 + wc * 64 + nt * 16 + lrow;
            float bias_v = bias[n];
            int hh = n >> 6, c = n & 63;
#pragma unroll
            for (int j = 0; j < 4; j++) {
                int m = am0 + wr * 64 + mt * 16 + rbase + j;
                float v = acc[mt][nt][j] + bias_v;
                int b = m >> 11, s = m & 2047;
                if (wi == 0) {
                    size_t idx = ((size_t)(b * NH + hh) * SEQ + s) * HD + c;
                    qf[idx] = f32_to_f16(v);
                } else if (wi == 1) {
                    size_t idx = ((size_t)(b * NH + hh) * SEQ + s) * HD + c;
                    kf[idx] = f32_to_f16(v);
                } else {
                    size_t idx = ((size_t)(b * NH + hh) * HD + c) * SEQ + s;
                    vt[idx] = f32_to_f16(v);
                }
            }
        }
}

// ---------------- K3: output projection GEMM ----------------
__global__ __launch_bounds__(256) void k_gemm_out(
    const u16* __restrict__ af_in, const u16* __restrict__ wt,
    const float* __restrict__ bo, float* __restrict__ out) {
    __shared__ u16 As[128 * 64];
    __shared__ u16 Bs[128 * 64];
    int lane = threadIdx.x & 63, w = threadIdx.x >> 6;
    int wr = w >> 1, wc = w & 1;
    int lrow = lane & 15, rbase = (lane >> 4) * 4;
    int lin = blockIdx.y * 8 + blockIdx.x;
    int lin2 = (lin & 7) * 64 + (lin >> 3);
    int bx = lin2 % 8, by = lin2 / 8;
    int am0 = by * 128;
    int n0 = bx * 128;
    const u16* bmat = wt + ((size_t)3 << 20);

    GEMM_KLOOP(af_in, bmat, am0, n0)

#pragma unroll
    for (int mt = 0; mt < 4; mt++)
#pragma unroll
        for (int nt = 0; nt < 4; nt++) {
            int n = n0 + wc * 64 + nt * 16 + lrow;
            float bias_v = bo[n];
#pragma unroll
            for (int j = 0; j < 4; j++) {
                int m = am0 + wr * 64 + mt * 16 + rbase + j;
                out[(size_t)m * 1024 + n] = acc[mt][nt][j] + bias_v;
            }
        }
}

// ---------------- K2: fused attention, swapped QK^T (mfma(K,Q)) ----------------
// One wg = one (b,h, 16-row Q tile). 8 waves, each owns 256 K-columns.
// acc lane layout: P[kcol = rbase+j][qrow = lrow] -> row-reduction is lane-local,
// single-barrier softmax, float4 attn stores, packed b64 PV staging.
#define NW 8
__global__ __launch_bounds__(512, 4) void k_attn(
    const u16* __restrict__ qf, const u16* __restrict__ kf, const u16* __restrict__ vt,
    float* __restrict__ attn_out, u16* __restrict__ cf) {
    __shared__ float2 sm_ms[NW][16];       // (max, sum) per wave per qrow
    __shared__ u16 p_lds[NW][16][40];
    __shared__ float ctx_red[NW][16][68];

    int w = threadIdx.x >> 6, lane = threadIdx.x & 63;
    // XCD-chunked swizzle: 8192 wgs -> 1024/XCD = 8 heads/XCD (K/V L2 reuse)
    int bid0 = blockIdx.x;
    int bid = (bid0 & 7) * 1024 + (bid0 >> 3);
    int qt = bid & 127, bh = bid >> 7;
    int q0 = qt * 16;
    int lrow = lane & 15, lk8 = (lane >> 4) * 8, rbase = (lane >> 4) * 4;

    const u16* qp  = qf + (size_t)bh * SEQ * HD;
    const u16* kfp = kf + (size_t)bh * SEQ * HD;
    const u16* vtp = vt + (size_t)bh * HD * SEQ;

    // Q as B-operand fragments (B[col=qrow][k]), 2 k-steps covering hd=64
    short8 aq[2];
#pragma unroll
    for (int kk = 0; kk < 2; kk++) {
        size_t o = (size_t)(q0 + lrow) * HD + kk * 32 + lk8;
        aq[kk] = *(const short8*)(qp + o);
    }

    f32x4 acc[16];
#pragma unroll
    for (int t = 0; t < 16; t++) acc[t] = (f32x4)0.f;

    int c0w = w * 256;
    int laneoff = lrow * HD + lk8;
#pragma unroll
    for (int t = 0; t < 16; t++) {
        int col0 = c0w + t * 16;
        const u16* kbase = kfp + (size_t)col0 * HD + laneoff;
#pragma unroll
        for (int kk = 0; kk < 2; kk++) {
            short8 bk_ = *(const short8*)(kbase + kk * 32);
            // swapped: A = K-tile (rows = kcols), B = Q (cols = qrows)
            acc[t] = __builtin_amdgcn_mfma_f32_16x16x32_f16(bk_, aq[kk], acc[t], 0, 0, 0);
        }
    }

    // in-lane row max over this wave's 256 kcols (4 ILP chains), then 2 shuffles
    float m0_ = acc[0][0], m1_ = acc[0][1], m2_ = acc[0][2], m3_ = acc[0][3];
#pragma unroll
    for (int t = 1; t < 16; t++) {
        m0_ = fmaxf(m0_, acc[t][0]);
        m1_ = fmaxf(m1_, acc[t][1]);
        m2_ = fmaxf(m2_, acc[t][2]);
        m3_ = fmaxf(m3_, acc[t][3]);
    }
    float mv = fmaxf(fmaxf(m0_, m1_), fmaxf(m2_, m3_));
    mv = fmaxf(mv, __shfl_xor(mv, 16, 64));
    mv = fmaxf(mv, __shfl_xor(mv, 32, 64));   // mv = wave-local row max (all lanes)

    // exp with wave-local max + in-lane sum (4 chains), then 2 shuffles
    const float C = 0.125f * 1.44269504088896f;
    float s0_ = 0.f, s1_ = 0.f, s2_ = 0.f, s3_ = 0.f;
#pragma unroll
    for (int t = 0; t < 16; t++) {
        float e0 = exp2f((acc[t][0] - mv) * C);
        float e1 = exp2f((acc[t][1] - mv) * C);
        float e2 = exp2f((acc[t][2] - mv) * C);
        float e3 = exp2f((acc[t][3] - mv) * C);
        acc[t][0] = e0; acc[t][1] = e1; acc[t][2] = e2; acc[t][3] = e3;
        s0_ += e0; s1_ += e1; s2_ += e2; s3_ += e3;
    }
    float sv = (s0_ + s1_) + (s2_ + s3_);
    sv += __shfl_xor(sv, 16, 64);
    sv += __shfl_xor(sv, 32, 64);             // sv = wave-local row sum (all lanes)

    if (lane < 16) sm_ms[w][lrow] = make_float2(mv, sv);
    __syncthreads();                          // ONE barrier for softmax exchange

    // global max & rescaled denominator
    float M = sm_ms[0][lrow].x;
#pragma unroll
    for (int w2 = 1; w2 < NW; w2++) M = fmaxf(M, sm_ms[w2][lrow].x);
    float L = 0.f;
#pragma unroll
    for (int w2 = 0; w2 < NW; w2++) {
        float2 ms = sm_ms[w2][lrow];
        L += ms.y * exp2f((ms.x - M) * C);
    }
    float scale = exp2f((mv - M) * C) / L;

    // normalize + attn write: per lane 4 consecutive kcols -> float4 stores
    float* attn_row = attn_out + ((size_t)bh * SEQ + q0 + lrow) * SEQ + c0w + rbase;
#pragma unroll
    for (int t = 0; t < 16; t++) {
        float4 pv;
        pv.x = acc[t][0] * scale; pv.y = acc[t][1] * scale;
        pv.z = acc[t][2] * scale; pv.w = acc[t][3] * scale;
        acc[t][0] = pv.x; acc[t][1] = pv.y; acc[t][2] = pv.z; acc[t][3] = pv.w;
        *(float4*)(attn_row + t * 16) = pv;
    }

    // PV over this wave's 256 cols: stage P tile [16 qrows][32 kcols] via packed b64
    f32x4 cacc[4];
#pragma unroll
    for (int nt = 0; nt < 4; nt++) cacc[nt] = (f32x4)0.f;
#pragma unroll
    for (int c2 = 0; c2 < 8; c2++) {
#pragma unroll
        for (int tt = 0; tt < 2; tt++) {
            int t = c2 * 2 + tt;
            ushort4 pk;
            pk.x = f32_to_f16(acc[t][0]); pk.y = f32_to_f16(acc[t][1]);
            pk.z = f32_to_f16(acc[t][2]); pk.w = f32_to_f16(acc[t][3]);
            *(ushort4*)&p_lds[w][lrow][tt * 16 + rbase] = pk;
        }
        short8 pf = *(const short8*)&p_lds[w][lrow][lk8];
        int s0 = c0w + c2 * 32;
#pragma unroll
        for (int nt = 0; nt < 4; nt++) {
            short8 vf = *(const short8*)(vtp + (size_t)(nt * 16 + lrow) * SEQ + s0 + lk8);
            cacc[nt] = __builtin_amdgcn_mfma_f32_16x16x32_f16(pf, vf, cacc[nt], 0, 0, 0);
        }
    }

    // cross-wave ctx reduce + write ctx fp16 ([B,S,D])
#pragma unroll
    for (int nt = 0; nt < 4; nt++)
#pragma unroll
        for (int j = 0; j < 4; j++)
            ctx_red[w][rbase + j][nt * 16 + lrow] = cacc[nt][j];
    __syncthreads();
    int b = bh >> 4, h = bh & 15;
    int e0 = threadIdx.x * 2;
#pragma unroll
    for (int q = 0; q < 2; q++) {
        int e = e0 + q;
        int r = e >> 6, c = e & 63;
        float s = 0.f;
#pragma unroll
        for (int w2 = 0; w2 < NW; w2++) s += ctx_red[w2][r][c];
        size_t idx = ((size_t)b * SEQ + q0 + r) * DM + h * HD + c;
        cf[idx] = f32_to_f16(s);
    }
}

extern "C" void kernel_launch(void* const* d_in, const int* in_sizes, int n_in,
                              void* d_out, int out_size, void* d_ws, size_t ws_size,
                              hipStream_t stream) {
    const float* x  = (const float*)d_in[0];
    const float* wq = (const float*)d_in[1];
    const float* bq = (const float*)d_in[2];
    const float* wk = (const float*)d_in[3];
    const float* bk = (const float*)d_in[4];
    const float* wv = (const float*)d_in[5];
    const float* bv = (const float*)d_in[6];
    const float* wo = (const float*)d_in[7];
    const float* bo = (const float*)d_in[8];

    float* out  = (float*)d_out;
    float* attn = out + (size_t)BATCH * SEQ * DM;

    char* ws = (char*)d_ws;
    const size_t MB = 1u << 20;
    u16* x16  = (u16*)(ws + 0 * MB);    // 16 MiB
    u16* wt16 = (u16*)(ws + 16 * MB);   // 8 MiB (4 weights, [n][k], fp16)
    u16* qf   = (u16*)(ws + 24 * MB);   // 16 MiB
    u16* kf   = (u16*)(ws + 40 * MB);   // 16 MiB
    u16* vt   = (u16*)(ws + 56 * MB);   // 16 MiB
    u16* cf   = (u16*)(ws + 72 * MB);   // 16 MiB

    int n4 = BATCH * SEQ * DM / 4;
    k_split_x<<<(n4 + 255) / 256, 256, 0, stream>>>((const float4*)x, (ushort4*)x16, n4);
    k_split_w<<<4096, 256, 0, stream>>>(wq, wk, wv, wo, wt16);
    k_gemm_qkv<<<dim3(24, 64), 256, 0, stream>>>(x16, wt16, bq, bk, bv, qf, kf, vt);
    k_attn<<<BATCH * NH * (SEQ / 16), 512, 0, stream>>>(qf, kf, vt, attn, cf);
    k_gemm_out<<<dim3(8, 64), 256, 0, stream>>>(cf, wt16, bo, out);
}

// Round 7
// 634.362 us; speedup vs baseline: 1.2184x; 1.2184x over previous
//
#include <hip/hip_runtime.h>
#include <hip/hip_bf16.h>
#include <stdint.h>

typedef __attribute__((ext_vector_type(8))) short short8;
typedef __attribute__((ext_vector_type(4))) float f32x4;
typedef unsigned short u16;

#define BATCH 4
#define NH    16
#define SEQ   2048
#define DM    1024
#define HD    64
#define HSZ   131072   // SEQ*HD, u16 elems per head

__device__ __forceinline__ u16 f32_to_f16(float f) {
    _Float16 h = (_Float16)f;
    return __builtin_bit_cast(unsigned short, h);
}
__device__ __forceinline__ float f16_to_f32(u16 u) {
    _Float16 h = __builtin_bit_cast(_Float16, u);
    return (float)h;
}

__device__ __forceinline__ void gload_lds16(const void* g, void* l) {
    __builtin_amdgcn_global_load_lds(
        (const __attribute__((address_space(1))) void*)g,
        (__attribute__((address_space(3))) void*)l, 16, 0, 0);
}

// Fragment-tiled indices (K/Q use A/B 16x32 frag order; V uses PV B-frag order):
// kqidx: [bh][s>>4][c>>5][lane=(s&15)|(((c>>3)&3)<<4)][elem=c&7]
__device__ __forceinline__ size_t kq_idx(int s, int c) {
    return (size_t)(s >> 4) * 1024 + (size_t)(c >> 5) * 512 +
           (size_t)(((s & 15) | (((c >> 3) & 3) << 4))) * 8 + (c & 7);
}
// vidx: [bh][s>>5][c>>4][lane=(c&15)|(((s>>3)&3)<<4)][elem=s&7]
__device__ __forceinline__ size_t v_idx(int s, int c) {
    return (size_t)(s >> 5) * 2048 + (size_t)(c >> 4) * 512 +
           (size_t)(((c & 15) | (((s >> 3) & 3) << 4))) * 8 + (s & 7);
}

// ---------------- K0a: convert x to fp16 ----------------
__global__ void k_split_x(const float4* __restrict__ x, ushort4* __restrict__ xf, int n4) {
    int i = blockIdx.x * 256 + threadIdx.x;
    if (i >= n4) return;
    float4 v = x[i];
    float f[4] = {v.x, v.y, v.z, v.w};
    ushort4 h;
    u16* hp = (u16*)&h;
#pragma unroll
    for (int j = 0; j < 4; j++) hp[j] = f32_to_f16(f[j]);
    xf[i] = h;
}

// ---------------- K0b: transpose + convert the 4 weight matrices to fp16 ----------------
__global__ void k_split_w(const float* __restrict__ w0, const float* __restrict__ w1,
                          const float* __restrict__ w2, const float* __restrict__ w3,
                          u16* __restrict__ wt) {
    __shared__ float tile[32][33];
    int bx = blockIdx.x;
    int wi = bx >> 10;
    int t  = bx & 1023;
    int kt = t >> 5, nt = t & 31;
    const float* w = (wi == 0) ? w0 : (wi == 1) ? w1 : (wi == 2) ? w2 : w3;
    int tx = threadIdx.x & 31, ty = threadIdx.x >> 5;
#pragma unroll
    for (int i = 0; i < 4; i++) {
        int r = ty + i * 8;
        tile[r][tx] = w[(size_t)(kt * 32 + r) * 1024 + nt * 32 + tx];
    }
    __syncthreads();
    size_t base = ((size_t)wi << 20);
#pragma unroll
    for (int i = 0; i < 4; i++) {
        int r = ty + i * 8;
        size_t dst = base + (size_t)(nt * 32 + r) * 1024 + kt * 32 + tx;
        wt[dst] = f32_to_f16(tile[tx][r]);
    }
}

// ================= m97-style 128x128 GEMM core (unchanged) =================
#define GEMM_KLOOP(Aptr, Bptr, am0, bn0)                                              \
    f32x4 acc[4][4];                                                                   \
    _Pragma("unroll")                                                                  \
    for (int mt = 0; mt < 4; mt++)                                                     \
        _Pragma("unroll")                                                              \
        for (int nt = 0; nt < 4; nt++) acc[mt][nt] = (f32x4)0.f;                       \
    int rowc = lane >> 3;                                                              \
    int slx  = (lane & 7) ^ rowc;   /* pre-swizzled source slot */                     \
    int kx   = slx << 3;                                                               \
    for (int k0 = 0; k0 < 1024; k0 += 64) {                                            \
        _Pragma("unroll")                                                              \
        for (int i = 0; i < 4; i++) {                                                  \
            int c = w * 4 + i;                                                         \
            int row = c * 8 + rowc;                                                    \
            gload_lds16(Aptr + (size_t)(am0 + row) * 1024 + k0 + kx,                   \
                        (char*)As + c * 1024 + lane * 16);                             \
            gload_lds16(Bptr + (size_t)(bn0 + row) * 1024 + k0 + kx,                   \
                        (char*)Bs + c * 1024 + lane * 16);                             \
        }                                                                              \
        __syncthreads();                                                               \
        _Pragma("unroll")                                                              \
        for (int kk = 0; kk < 2; kk++) {                                               \
            short8 af[4], bf[4];                                                       \
            _Pragma("unroll")                                                          \
            for (int mt = 0; mt < 4; mt++) {                                           \
                int row = wr * 64 + mt * 16 + lrow;                                    \
                int slot = (kk * 4 + (lane >> 4)) ^ (row & 7);                         \
                af[mt] = *(const short8*)(As + row * 64 + slot * 8);                   \
            }                                                                          \
            _Pragma("unroll")                                                          \
            for (int nt = 0; nt < 4; nt++) {                                           \
                int row = wc * 64 + nt * 16 + lrow;                                    \
                int slot = (kk * 4 + (lane >> 4)) ^ (row & 7);                         \
                bf[nt] = *(const short8*)(Bs + row * 64 + slot * 8);                   \
            }                                                                          \
            _Pragma("unroll")                                                          \
            for (int mt = 0; mt < 4; mt++)                                             \
                _Pragma("unroll")                                                      \
                for (int nt = 0; nt < 4; nt++)                                         \
                    acc[mt][nt] = __builtin_amdgcn_mfma_f32_16x16x32_f16(              \
                        af[mt], bf[nt], acc[mt][nt], 0, 0, 0);                         \
        }                                                                              \
        __syncthreads();                                                               \
    }

// ---------------- K1: QKV projection GEMM ----------------
__global__ __launch_bounds__(256) void k_gemm_qkv(
    const u16* __restrict__ xf, const u16* __restrict__ wt,
    const float* __restrict__ bq, const float* __restrict__ bk, const float* __restrict__ bv,
    u16* __restrict__ qf, u16* __restrict__ kf, u16* __restrict__ vt) {
    __shared__ u16 As[128 * 64];
    __shared__ u16 Bs[128 * 64];
    int lane = threadIdx.x & 63, w = threadIdx.x >> 6;
    int wr = w >> 1, wc = w & 1;
    int lrow = lane & 15, rbase = (lane >> 4) * 4;
    int lin = blockIdx.y * 24 + blockIdx.x;
    int lin2 = (lin & 7) * 192 + (lin >> 3);
    int bx = lin2 % 24, by = lin2 / 24;
    int am0 = by * 128;
    int n0 = bx * 128;
    int wi = n0 >> 10;
    int nn0 = n0 & 1023;
    const u16* bmat = wt + ((size_t)wi << 20);

    GEMM_KLOOP(xf, bmat, am0, nn0)

    const float* bias = (wi == 0) ? bq : (wi == 1) ? bk : bv;
#pragma unroll
    for (int mt = 0; mt < 4; mt++)
#pragma unroll
        for (int nt = 0; nt < 4; nt++) {
            int n = nn0 + wc * 64 + nt * 16 + lrow;
            float bias_v = bias[n];
            int hh = n >> 6, c = n & 63;
#pragma unroll
            for (int j = 0; j < 4; j++) {
                int m = am0 + wr * 64 + mt * 16 + rbase + j;
                float v = acc[mt][nt][j] + bias_v;
                int b = m >> 11, s = m & 2047;
                size_t hb = (size_t)(b * NH + hh) * HSZ;
                if (wi == 0) {
                    qf[hb + kq_idx(s, c)] = f32_to_f16(v);
                } else if (wi == 1) {
                    kf[hb + kq_idx(s, c)] = f32_to_f16(v);
                } else {
                    vt[hb + v_idx(s, c)] = f32_to_f16(v);
                }
            }
        }
}

// ---------------- K3: output projection GEMM ----------------
__global__ __launch_bounds__(256) void k_gemm_out(
    const u16* __restrict__ af_in, const u16* __restrict__ wt,
    const float* __restrict__ bo, float* __restrict__ out) {
    __shared__ u16 As[128 * 64];
    __shared__ u16 Bs[128 * 64];
    int lane = threadIdx.x & 63, w = threadIdx.x >> 6;
    int wr = w >> 1, wc = w & 1;
    int lrow = lane & 15, rbase = (lane >> 4) * 4;
    int lin = blockIdx.y * 8 + blockIdx.x;
    int lin2 = (lin & 7) * 64 + (lin >> 3);
    int bx = lin2 % 8, by = lin2 / 8;
    int am0 = by * 128;
    int n0 = bx * 128;
    const u16* bmat = wt + ((size_t)3 << 20);

    GEMM_KLOOP(af_in, bmat, am0, n0)

#pragma unroll
    for (int mt = 0; mt < 4; mt++)
#pragma unroll
        for (int nt = 0; nt < 4; nt++) {
            int n = n0 + wc * 64 + nt * 16 + lrow;
            float bias_v = bo[n];
#pragma unroll
            for (int j = 0; j < 4; j++) {
                int m = am0 + wr * 64 + mt * 16 + rbase + j;
                out[(size_t)m * 1024 + n] = acc[mt][nt][j] + bias_v;
            }
        }
}

// ---------------- K2: fused attention, swapped QK^T + fragment-tiled K/V/Q ----------------
// One wg = one (b,h, 16-row Q tile). 8 waves, each owns 256 K-columns.
// All K/V/Q loads are fully-coalesced 1KB bursts (lane*8 contiguous).
#define NW 8
__global__ __launch_bounds__(512, 4) void k_attn(
    const u16* __restrict__ qf, const u16* __restrict__ kf, const u16* __restrict__ vt,
    float* __restrict__ attn_out, u16* __restrict__ cf) {
    __shared__ float2 sm_ms[NW][16];       // (max, sum) per wave per qrow
    __shared__ u16 p_lds[NW][16][40];
    __shared__ float ctx_red[NW][16][68];

    int w = threadIdx.x >> 6, lane = threadIdx.x & 63;
    // XCD-chunked swizzle: 8192 wgs -> 1024/XCD = 8 heads/XCD (K/V L2 reuse)
    int bid0 = blockIdx.x;
    int bid = (bid0 & 7) * 1024 + (bid0 >> 3);
    int qt = bid & 127, bh = bid >> 7;
    int q0 = qt * 16;
    int lrow = lane & 15, lk8 = (lane >> 4) * 8, rbase = (lane >> 4) * 4;

    const u16* qp  = qf + (size_t)bh * HSZ;
    const u16* kfp = kf + (size_t)bh * HSZ;
    const u16* vtp = vt + (size_t)bh * HSZ;

    // Q as B-operand fragments, fragment-tiled: contiguous per wave
    short8 aq[2];
#pragma unroll
    for (int kk = 0; kk < 2; kk++)
        aq[kk] = *(const short8*)(qp + (size_t)qt * 1024 + kk * 512 + lane * 8);

    f32x4 acc[16];
#pragma unroll
    for (int t = 0; t < 16; t++) acc[t] = (f32x4)0.f;

    int c0w = w * 256;
    int tbase = c0w >> 4;   // K tile base for this wave
#pragma unroll
    for (int t = 0; t < 16; t++) {
        const u16* kb = kfp + (size_t)(tbase + t) * 1024 + lane * 8;
#pragma unroll
        for (int kk = 0; kk < 2; kk++) {
            short8 bk_ = *(const short8*)(kb + kk * 512);
            // swapped: A = K-tile (rows = kcols), B = Q (cols = qrows)
            acc[t] = __builtin_amdgcn_mfma_f32_16x16x32_f16(bk_, aq[kk], acc[t], 0, 0, 0);
        }
    }

    // in-lane row max over this wave's 256 kcols (4 ILP chains), then 2 shuffles
    float m0_ = acc[0][0], m1_ = acc[0][1], m2_ = acc[0][2], m3_ = acc[0][3];
#pragma unroll
    for (int t = 1; t < 16; t++) {
        m0_ = fmaxf(m0_, acc[t][0]);
        m1_ = fmaxf(m1_, acc[t][1]);
        m2_ = fmaxf(m2_, acc[t][2]);
        m3_ = fmaxf(m3_, acc[t][3]);
    }
    float mv = fmaxf(fmaxf(m0_, m1_), fmaxf(m2_, m3_));
    mv = fmaxf(mv, __shfl_xor(mv, 16, 64));
    mv = fmaxf(mv, __shfl_xor(mv, 32, 64));   // wave-local row max

    const float C = 0.125f * 1.44269504088896f;
    float s0_ = 0.f, s1_ = 0.f, s2_ = 0.f, s3_ = 0.f;
#pragma unroll
    for (int t = 0; t < 16; t++) {
        float e0 = exp2f((acc[t][0] - mv) * C);
        float e1 = exp2f((acc[t][1] - mv) * C);
        float e2 = exp2f((acc[t][2] - mv) * C);
        float e3 = exp2f((acc[t][3] - mv) * C);
        acc[t][0] = e0; acc[t][1] = e1; acc[t][2] = e2; acc[t][3] = e3;
        s0_ += e0; s1_ += e1; s2_ += e2; s3_ += e3;
    }
    float sv = (s0_ + s1_) + (s2_ + s3_);
    sv += __shfl_xor(sv, 16, 64);
    sv += __shfl_xor(sv, 32, 64);             // wave-local row sum

    if (lane < 16) sm_ms[w][lrow] = make_float2(mv, sv);
    __syncthreads();                          // ONE barrier for softmax exchange

    float M = sm_ms[0][lrow].x;
#pragma unroll
    for (int w2 = 1; w2 < NW; w2++) M = fmaxf(M, sm_ms[w2][lrow].x);
    float L = 0.f;
#pragma unroll
    for (int w2 = 0; w2 < NW; w2++) {
        float2 ms = sm_ms[w2][lrow];
        L += ms.y * exp2f((ms.x - M) * C);
    }
    float scale = exp2f((mv - M) * C) / L;

    // normalize + attn write: per lane 4 consecutive kcols -> float4 stores
    float* attn_row = attn_out + ((size_t)bh * SEQ + q0 + lrow) * SEQ + c0w + rbase;
#pragma unroll
    for (int t = 0; t < 16; t++) {
        float4 pv;
        pv.x = acc[t][0] * scale; pv.y = acc[t][1] * scale;
        pv.z = acc[t][2] * scale; pv.w = acc[t][3] * scale;
        acc[t][0] = pv.x; acc[t][1] = pv.y; acc[t][2] = pv.z; acc[t][3] = pv.w;
        *(float4*)(attn_row + t * 16) = pv;
    }

    // PV over this wave's 256 cols; V loads are coalesced 1KB bursts
    f32x4 cacc[4];
#pragma unroll
    for (int nt = 0; nt < 4; nt++) cacc[nt] = (f32x4)0.f;
    int cbase = c0w >> 5;   // V tile base for this wave
#pragma unroll
    for (int c2 = 0; c2 < 8; c2++) {
#pragma unroll
        for (int tt = 0; tt < 2; tt++) {
            int t = c2 * 2 + tt;
            ushort4 pk;
            pk.x = f32_to_f16(acc[t][0]); pk.y = f32_to_f16(acc[t][1]);
            pk.z = f32_to_f16(acc[t][2]); pk.w = f32_to_f16(acc[t][3]);
            *(ushort4*)&p_lds[w][lrow][tt * 16 + rbase] = pk;
        }
        short8 pf = *(const short8*)&p_lds[w][lrow][lk8];
        const u16* vb = vtp + (size_t)(cbase + c2) * 2048 + lane * 8;
#pragma unroll
        for (int nt = 0; nt < 4; nt++) {
            short8 vf = *(const short8*)(vb + nt * 512);
            cacc[nt] = __builtin_amdgcn_mfma_f32_16x16x32_f16(pf, vf, cacc[nt], 0, 0, 0);
        }
    }

    // cross-wave ctx reduce + write ctx fp16 ([B,S,D] row-major for out-proj)
#pragma unroll
    for (int nt = 0; nt < 4; nt++)
#pragma unroll
        for (int j = 0; j < 4; j++)
            ctx_red[w][rbase + j][nt * 16 + lrow] = cacc[nt][j];
    __syncthreads();
    int b = bh >> 4, h = bh & 15;
    int e0 = threadIdx.x * 2;
#pragma unroll
    for (int q = 0; q < 2; q++) {
        int e = e0 + q;
        int r = e >> 6, c = e & 63;
        float s = 0.f;
#pragma unroll
        for (int w2 = 0; w2 < NW; w2++) s += ctx_red[w2][r][c];
        size_t idx = ((size_t)b * SEQ + q0 + r) * DM + h * HD + c;
        cf[idx] = f32_to_f16(s);
    }
}

extern "C" void kernel_launch(void* const* d_in, const int* in_sizes, int n_in,
                              void* d_out, int out_size, void* d_ws, size_t ws_size,
                              hipStream_t stream) {
    const float* x  = (const float*)d_in[0];
    const float* wq = (const float*)d_in[1];
    const float* bq = (const float*)d_in[2];
    const float* wk = (const float*)d_in[3];
    const float* bk = (const float*)d_in[4];
    const float* wv = (const float*)d_in[5];
    const float* bv = (const float*)d_in[6];
    const float* wo = (const float*)d_in[7];
    const float* bo = (const float*)d_in[8];

    float* out  = (float*)d_out;
    float* attn = out + (size_t)BATCH * SEQ * DM;

    char* ws = (char*)d_ws;
    const size_t MB = 1u << 20;
    u16* x16  = (u16*)(ws + 0 * MB);    // 16 MiB
    u16* wt16 = (u16*)(ws + 16 * MB);   // 8 MiB (4 weights, [n][k], fp16)
    u16* qf   = (u16*)(ws + 24 * MB);   // 16 MiB (fragment-tiled)
    u16* kf   = (u16*)(ws + 40 * MB);   // 16 MiB (fragment-tiled)
    u16* vt   = (u16*)(ws + 56 * MB);   // 16 MiB (fragment-tiled)
    u16* cf   = (u16*)(ws + 72 * MB);   // 16 MiB

    int n4 = BATCH * SEQ * DM / 4;
    k_split_x<<<(n4 + 255) / 256, 256, 0, stream>>>((const float4*)x, (ushort4*)x16, n4);
    k_split_w<<<4096, 256, 0, stream>>>(wq, wk, wv, wo, wt16);
    k_gemm_qkv<<<dim3(24, 64), 256, 0, stream>>>(x16, wt16, bq, bk, bv, qf, kf, vt);
    k_attn<<<BATCH * NH * (SEQ / 16), 512, 0, stream>>>(qf, kf, vt, attn, cf);
    k_gemm_out<<<dim3(8, 64), 256, 0, stream>>>(cf, wt16, bo, out);
}

// Round 9
// 554.358 us; speedup vs baseline: 1.3942x; 1.1443x over previous
//
#include <hip/hip_runtime.h>
#include <hip/hip_bf16.h>
#include <stdint.h>

typedef __attribute__((ext_vector_type(8))) short short8;
typedef __attribute__((ext_vector_type(4))) float f32x4;
typedef unsigned short u16;

#define BATCH 4
#define NH    16
#define SEQ   2048
#define DM    1024
#define HD    64
#define HSZ   131072   // SEQ*HD, u16 elems per head

__device__ __forceinline__ u16 f32_to_f16(float f) {
    _Float16 h = (_Float16)f;
    return __builtin_bit_cast(unsigned short, h);
}
__device__ __forceinline__ float f16_to_f32(u16 u) {
    _Float16 h = __builtin_bit_cast(_Float16, u);
    return (float)h;
}

__device__ __forceinline__ void gload_lds16(const void* g, void* l) {
    __builtin_amdgcn_global_load_lds(
        (const __attribute__((address_space(1))) void*)g,
        (__attribute__((address_space(3))) void*)l, 16, 0, 0);
}

// Fragment-tiled indices (K/Q use A/B 16x32 frag order; V uses PV B-frag order):
__device__ __forceinline__ size_t kq_idx(int s, int c) {
    return (size_t)(s >> 4) * 1024 + (size_t)(c >> 5) * 512 +
           (size_t)(((s & 15) | (((c >> 3) & 3) << 4))) * 8 + (c & 7);
}
__device__ __forceinline__ size_t v_idx(int s, int c) {
    return (size_t)(s >> 5) * 2048 + (size_t)(c >> 4) * 512 +
           (size_t)(((c & 15) | (((s >> 3) & 3) << 4))) * 8 + (s & 7);
}

// ---------------- K0a: convert x to fp16 ----------------
__global__ void k_split_x(const float4* __restrict__ x, ushort4* __restrict__ xf, int n4) {
    int i = blockIdx.x * 256 + threadIdx.x;
    if (i >= n4) return;
    float4 v = x[i];
    float f[4] = {v.x, v.y, v.z, v.w};
    ushort4 h;
    u16* hp = (u16*)&h;
#pragma unroll
    for (int j = 0; j < 4; j++) hp[j] = f32_to_f16(f[j]);
    xf[i] = h;
}

// ---------------- K0b: transpose + convert the 4 weight matrices to fp16 ----------------
__global__ void k_split_w(const float* __restrict__ w0, const float* __restrict__ w1,
                          const float* __restrict__ w2, const float* __restrict__ w3,
                          u16* __restrict__ wt) {
    __shared__ float tile[32][33];
    int bx = blockIdx.x;
    int wi = bx >> 10;
    int t  = bx & 1023;
    int kt = t >> 5, nt = t & 31;
    const float* w = (wi == 0) ? w0 : (wi == 1) ? w1 : (wi == 2) ? w2 : w3;
    int tx = threadIdx.x & 31, ty = threadIdx.x >> 5;
#pragma unroll
    for (int i = 0; i < 4; i++) {
        int r = ty + i * 8;
        tile[r][tx] = w[(size_t)(kt * 32 + r) * 1024 + nt * 32 + tx];
    }
    __syncthreads();
    size_t base = ((size_t)wi << 20);
#pragma unroll
    for (int i = 0; i < 4; i++) {
        int r = ty + i * 8;
        size_t dst = base + (size_t)(nt * 32 + r) * 1024 + kt * 32 + tx;
        wt[dst] = f32_to_f16(tile[tx][r]);
    }
}

// ================= m97-style 128x128 GEMM core (unchanged) =================
#define GEMM_KLOOP(Aptr, Bptr, am0, bn0)                                              \
    f32x4 acc[4][4];                                                                   \
    _Pragma("unroll")                                                                  \
    for (int mt = 0; mt < 4; mt++)                                                     \
        _Pragma("unroll")                                                              \
        for (int nt = 0; nt < 4; nt++) acc[mt][nt] = (f32x4)0.f;                       \
    int rowc = lane >> 3;                                                              \
    int slx  = (lane & 7) ^ rowc;   /* pre-swizzled source slot */                     \
    int kx   = slx << 3;                                                               \
    for (int k0 = 0; k0 < 1024; k0 += 64) {                                            \
        _Pragma("unroll")                                                              \
        for (int i = 0; i < 4; i++) {                                                  \
            int c = w * 4 + i;                                                         \
            int row = c * 8 + rowc;                                                    \
            gload_lds16(Aptr + (size_t)(am0 + row) * 1024 + k0 + kx,                   \
                        (char*)As + c * 1024 + lane * 16);                             \
            gload_lds16(Bptr + (size_t)(bn0 + row) * 1024 + k0 + kx,                   \
                        (char*)Bs + c * 1024 + lane * 16);                             \
        }                                                                              \
        __syncthreads();                                                               \
        _Pragma("unroll")                                                              \
        for (int kk = 0; kk < 2; kk++) {                                               \
            short8 af[4], bf[4];                                                       \
            _Pragma("unroll")                                                          \
            for (int mt = 0; mt < 4; mt++) {                                           \
                int row = wr * 64 + mt * 16 + lrow;                                    \
                int slot = (kk * 4 + (lane >> 4)) ^ (row & 7);                         \
                af[mt] = *(const short8*)(As + row * 64 + slot * 8);                   \
            }                                                                          \
            _Pragma("unroll")                                                          \
            for (int nt = 0; nt < 4; nt++) {                                           \
                int row = wc * 64 + nt * 16 + lrow;                                    \
                int slot = (kk * 4 + (lane >> 4)) ^ (row & 7);                         \
                bf[nt] = *(const short8*)(Bs + row * 64 + slot * 8);                   \
            }                                                                          \
            _Pragma("unroll")                                                          \
            for (int mt = 0; mt < 4; mt++)                                             \
                _Pragma("unroll")                                                      \
                for (int nt = 0; nt < 4; nt++)                                         \
                    acc[mt][nt] = __builtin_amdgcn_mfma_f32_16x16x32_f16(              \
                        af[mt], bf[nt], acc[mt][nt], 0, 0, 0);                         \
        }                                                                              \
        __syncthreads();                                                               \
    }

// ---------------- K1: QKV projection GEMM ----------------
__global__ __launch_bounds__(256) void k_gemm_qkv(
    const u16* __restrict__ xf, const u16* __restrict__ wt,
    const float* __restrict__ bq, const float* __restrict__ bk, const float* __restrict__ bv,
    u16* __restrict__ qf, u16* __restrict__ kf, u16* __restrict__ vt) {
    __shared__ u16 As[128 * 64];
    __shared__ u16 Bs[128 * 64];
    int lane = threadIdx.x & 63, w = threadIdx.x >> 6;
    int wr = w >> 1, wc = w & 1;
    int lrow = lane & 15, rbase = (lane >> 4) * 4;
    int lin = blockIdx.y * 24 + blockIdx.x;
    int lin2 = (lin & 7) * 192 + (lin >> 3);
    int bx = lin2 % 24, by = lin2 / 24;
    int am0 = by * 128;
    int n0 = bx * 128;
    int wi = n0 >> 10;
    int nn0 = n0 & 1023;
    const u16* bmat = wt + ((size_t)wi << 20);

    GEMM_KLOOP(xf, bmat, am0, nn0)

    const float* bias = (wi == 0) ? bq : (wi == 1) ? bk : bv;
#pragma unroll
    for (int mt = 0; mt < 4; mt++)
#pragma unroll
        for (int nt = 0; nt < 4; nt++) {
            int n = nn0 + wc * 64 + nt * 16 + lrow;
            float bias_v = bias[n];
            int hh = n >> 6, c = n & 63;
#pragma unroll
            for (int j = 0; j < 4; j++) {
                int m = am0 + wr * 64 + mt * 16 + rbase + j;
                float v = acc[mt][nt][j] + bias_v;
                int b = m >> 11, s = m & 2047;
                size_t hb = (size_t)(b * NH + hh) * HSZ;
                if (wi == 0) {
                    qf[hb + kq_idx(s, c)] = f32_to_f16(v);
                } else if (wi == 1) {
                    kf[hb + kq_idx(s, c)] = f32_to_f16(v);
                } else {
                    vt[hb + v_idx(s, c)] = f32_to_f16(v);
                }
            }
        }
}

// ---------------- K3: output projection GEMM ----------------
__global__ __launch_bounds__(256) void k_gemm_out(
    const u16* __restrict__ af_in, const u16* __restrict__ wt,
    const float* __restrict__ bo, float* __restrict__ out) {
    __shared__ u16 As[128 * 64];
    __shared__ u16 Bs[128 * 64];
    int lane = threadIdx.x & 63, w = threadIdx.x >> 6;
    int wr = w >> 1, wc = w & 1;
    int lrow = lane & 15, rbase = (lane >> 4) * 4;
    int lin = blockIdx.y * 8 + blockIdx.x;
    int lin2 = (lin & 7) * 64 + (lin >> 3);
    int bx = lin2 % 8, by = lin2 / 8;
    int am0 = by * 128;
    int n0 = bx * 128;
    const u16* bmat = wt + ((size_t)3 << 20);

    GEMM_KLOOP(af_in, bmat, am0, n0)

#pragma unroll
    for (int mt = 0; mt < 4; mt++)
#pragma unroll
        for (int nt = 0; nt < 4; nt++) {
            int n = n0 + wc * 64 + nt * 16 + lrow;
            float bias_v = bo[n];
#pragma unroll
            for (int j = 0; j < 4; j++) {
                int m = am0 + wr * 64 + mt * 16 + rbase + j;
                out[(size_t)m * 1024 + n] = acc[mt][nt][j] + bias_v;
            }
        }
}

// ---------------- K2: fused attention, swapped QK^T + software pipeline ----------------
// One wg = one (b,h, 16-row Q tile). 8 waves, each owns 256 K-columns.
// K: depth-4 register double-buffer. V: issue-early before softmax + depth-2 during PV.
// Normalize + attn store embedded in PV loop. setprio around MFMA clusters.
#define NW 8
__global__ __launch_bounds__(512, 4) void k_attn(
    const u16* __restrict__ qf, const u16* __restrict__ kf, const u16* __restrict__ vt,
    float* __restrict__ attn_out, u16* __restrict__ cf) {
    __shared__ float2 sm_ms[NW][16];       // (max, sum) per wave per qrow
    __shared__ u16 p_lds[NW][16][40];
    __shared__ float ctx_red[NW][16][68];

    int w = threadIdx.x >> 6, lane = threadIdx.x & 63;
    // XCD-chunked swizzle: 8192 wgs -> 1024/XCD = 8 heads/XCD (K/V L2 reuse)
    int bid0 = blockIdx.x;
    int bid = (bid0 & 7) * 1024 + (bid0 >> 3);
    int qt = bid & 127, bh = bid >> 7;
    int q0 = qt * 16;
    int lrow = lane & 15, lk8 = (lane >> 4) * 8, rbase = (lane >> 4) * 4;

    const u16* qp  = qf + (size_t)bh * HSZ;
    const u16* kfp = kf + (size_t)bh * HSZ;
    const u16* vtp = vt + (size_t)bh * HSZ;

    // Q as B-operand fragments, fragment-tiled: contiguous per wave
    short8 aq[2];
#pragma unroll
    for (int kk = 0; kk < 2; kk++)
        aq[kk] = *(const short8*)(qp + (size_t)qt * 1024 + kk * 512 + lane * 8);

    f32x4 acc[16];
#pragma unroll
    for (int t = 0; t < 16; t++) acc[t] = (f32x4)0.f;

    int c0w = w * 256;
    int tbase = c0w >> 4;   // K tile base for this wave
    const u16* kl = kfp + (size_t)tbase * 1024 + lane * 8;

    // ---- QK^T: depth-4 K-tile register pipeline (8 loads in flight) ----
    short8 kbuf[4][2];
#pragma unroll
    for (int t = 0; t < 4; t++) {
        kbuf[t][0] = *(const short8*)(kl + (size_t)t * 1024);
        kbuf[t][1] = *(const short8*)(kl + (size_t)t * 1024 + 512);
    }
#pragma unroll
    for (int t = 0; t < 16; t++) {
        short8 b0 = kbuf[t & 3][0];
        short8 b1 = kbuf[t & 3][1];
        if (t < 12) {
            kbuf[t & 3][0] = *(const short8*)(kl + (size_t)(t + 4) * 1024);
            kbuf[t & 3][1] = *(const short8*)(kl + (size_t)(t + 4) * 1024 + 512);
        }
        __builtin_amdgcn_s_setprio(1);
        acc[t] = __builtin_amdgcn_mfma_f32_16x16x32_f16(b0, aq[0], acc[t], 0, 0, 0);
        acc[t] = __builtin_amdgcn_mfma_f32_16x16x32_f16(b1, aq[1], acc[t], 0, 0, 0);
        __builtin_amdgcn_s_setprio(0);
    }

    // ---- V issue-early: first c2-group's loads hide under softmax ----
    int cbase = c0w >> 5;   // V tile base for this wave
    const u16* vl = vtp + (size_t)cbase * 2048 + lane * 8;
    short8 vbuf[2][4];
#pragma unroll
    for (int nt = 0; nt < 4; nt++) vbuf[0][nt] = *(const short8*)(vl + nt * 512);

    // ---- softmax: in-lane reduction + single barrier ----
    float m0_ = acc[0][0], m1_ = acc[0][1], m2_ = acc[0][2], m3_ = acc[0][3];
#pragma unroll
    for (int t = 1; t < 16; t++) {
        m0_ = fmaxf(m0_, acc[t][0]);
        m1_ = fmaxf(m1_, acc[t][1]);
        m2_ = fmaxf(m2_, acc[t][2]);
        m3_ = fmaxf(m3_, acc[t][3]);
    }
    float mv = fmaxf(fmaxf(m0_, m1_), fmaxf(m2_, m3_));
    mv = fmaxf(mv, __shfl_xor(mv, 16, 64));
    mv = fmaxf(mv, __shfl_xor(mv, 32, 64));   // wave-local row max

    const float C = 0.125f * 1.44269504088896f;
    float s0_ = 0.f, s1_ = 0.f, s2_ = 0.f, s3_ = 0.f;
#pragma unroll
    for (int t = 0; t < 16; t++) {
        float e0 = exp2f((acc[t][0] - mv) * C);
        float e1 = exp2f((acc[t][1] - mv) * C);
        float e2 = exp2f((acc[t][2] - mv) * C);
        float e3 = exp2f((acc[t][3] - mv) * C);
        acc[t][0] = e0; acc[t][1] = e1; acc[t][2] = e2; acc[t][3] = e3;
        s0_ += e0; s1_ += e1; s2_ += e2; s3_ += e3;
    }
    float sv = (s0_ + s1_) + (s2_ + s3_);
    sv += __shfl_xor(sv, 16, 64);
    sv += __shfl_xor(sv, 32, 64);             // wave-local row sum

    if (lane < 16) sm_ms[w][lrow] = make_float2(mv, sv);
    __syncthreads();                          // ONE barrier for softmax exchange

    float M = sm_ms[0][lrow].x;
#pragma unroll
    for (int w2 = 1; w2 < NW; w2++) M = fmaxf(M, sm_ms[w2][lrow].x);
    float L = 0.f;
#pragma unroll
    for (int w2 = 0; w2 < NW; w2++) {
        float2 ms = sm_ms[w2][lrow];
        L += ms.y * exp2f((ms.x - M) * C);
    }
    float scale = exp2f((mv - M) * C) / L;

    // ---- PV + embedded normalize + attn store, V depth-2 prefetch ----
    float* attn_row = attn_out + ((size_t)bh * SEQ + q0 + lrow) * SEQ + c0w + rbase;
    f32x4 cacc[4];
#pragma unroll
    for (int nt = 0; nt < 4; nt++) cacc[nt] = (f32x4)0.f;
#pragma unroll
    for (int c2 = 0; c2 < 8; c2++) {
        if (c2 < 7) {
#pragma unroll
            for (int nt = 0; nt < 4; nt++)
                vbuf[(c2 + 1) & 1][nt] =
                    *(const short8*)(vl + (size_t)(c2 + 1) * 2048 + nt * 512);
        }
#pragma unroll
        for (int tt = 0; tt < 2; tt++) {
            int t = c2 * 2 + tt;
            float4 pv;
            pv.x = acc[t][0] * scale; pv.y = acc[t][1] * scale;
            pv.z = acc[t][2] * scale; pv.w = acc[t][3] * scale;
            *(float4*)(attn_row + t * 16) = pv;
            ushort4 pk;
            pk.x = f32_to_f16(pv.x); pk.y = f32_to_f16(pv.y);
            pk.z = f32_to_f16(pv.z); pk.w = f32_to_f16(pv.w);
            *(ushort4*)&p_lds[w][lrow][tt * 16 + rbase] = pk;
        }
        short8 pf = *(const short8*)&p_lds[w][lrow][lk8];
        __builtin_amdgcn_s_setprio(1);
#pragma unroll
        for (int nt = 0; nt < 4; nt++)
            cacc[nt] = __builtin_amdgcn_mfma_f32_16x16x32_f16(pf, vbuf[c2 & 1][nt], cacc[nt], 0, 0, 0);
        __builtin_amdgcn_s_setprio(0);
    }

    // cross-wave ctx reduce + write ctx fp16 ([B,S,D] row-major for out-proj)
#pragma unroll
    for (int nt = 0; nt < 4; nt++)
#pragma unroll
        for (int j = 0; j < 4; j++)
            ctx_red[w][rbase + j][nt * 16 + lrow] = cacc[nt][j];
    __syncthreads();
    int b = bh >> 4, h = bh & 15;
    int e0 = threadIdx.x * 2;
#pragma unroll
    for (int q = 0; q < 2; q++) {
        int e = e0 + q;
        int r = e >> 6, c = e & 63;
        float s = 0.f;
#pragma unroll
        for (int w2 = 0; w2 < NW; w2++) s += ctx_red[w2][r][c];
        size_t idx = ((size_t)b * SEQ + q0 + r) * DM + h * HD + c;
        cf[idx] = f32_to_f16(s);
    }
}

extern "C" void kernel_launch(void* const* d_in, const int* in_sizes, int n_in,
                              void* d_out, int out_size, void* d_ws, size_t ws_size,
                              hipStream_t stream) {
    const float* x  = (const float*)d_in[0];
    const float* wq = (const float*)d_in[1];
    const float* bq = (const float*)d_in[2];
    const float* wk = (const float*)d_in[3];
    const float* bk = (const float*)d_in[4];
    const float* wv = (const float*)d_in[5];
    const float* bv = (const float*)d_in[6];
    const float* wo = (const float*)d_in[7];
    const float* bo = (const float*)d_in[8];

    float* out  = (float*)d_out;
    float* attn = out + (size_t)BATCH * SEQ * DM;

    char* ws = (char*)d_ws;
    const size_t MB = 1u << 20;
    u16* x16  = (u16*)(ws + 0 * MB);    // 16 MiB
    u16* wt16 = (u16*)(ws + 16 * MB);   // 8 MiB (4 weights, [n][k], fp16)
    u16* qf   = (u16*)(ws + 24 * MB);   // 16 MiB (fragment-tiled)
    u16* kf   = (u16*)(ws + 40 * MB);   // 16 MiB (fragment-tiled)
    u16* vt   = (u16*)(ws + 56 * MB);   // 16 MiB (fragment-tiled)
    u16* cf   = (u16*)(ws + 72 * MB);   // 16 MiB

    int n4 = BATCH * SEQ * DM / 4;
    k_split_x<<<(n4 + 255) / 256, 256, 0, stream>>>((const float4*)x, (ushort4*)x16, n4);
    k_split_w<<<4096, 256, 0, stream>>>(wq, wk, wv, wo, wt16);
    k_gemm_qkv<<<dim3(24, 64), 256, 0, stream>>>(x16, wt16, bq, bk, bv, qf, kf, vt);
    k_attn<<<BATCH * NH * (SEQ / 16), 512, 0, stream>>>(qf, kf, vt, attn, cf);
    k_gemm_out<<<dim3(8, 64), 256, 0, stream>>>(cf, wt16, bo, out);
}

// Round 11
// 435.259 us; speedup vs baseline: 1.7757x; 1.2736x over previous
//
#include <hip/hip_runtime.h>
#include <hip/hip_bf16.h>
#include <stdint.h>

typedef __attribute__((ext_vector_type(8))) short short8;
typedef __attribute__((ext_vector_type(4))) float f32x4;
typedef unsigned short u16;

#define BATCH 4
#define NH    16
#define SEQ   2048
#define DM    1024
#define HD    64
#define HSZ   131072   // SEQ*HD, u16 elems per head

__device__ __forceinline__ u16 f32_to_f16(float f) {
    _Float16 h = (_Float16)f;
    return __builtin_bit_cast(unsigned short, h);
}
__device__ __forceinline__ float f16_to_f32(u16 u) {
    _Float16 h = __builtin_bit_cast(_Float16, u);
    return (float)h;
}

__device__ __forceinline__ void gload_lds16(const void* g, void* l) {
    __builtin_amdgcn_global_load_lds(
        (const __attribute__((address_space(1))) void*)g,
        (__attribute__((address_space(3))) void*)l, 16, 0, 0);
}

// Fragment-tiled indices (K/Q use A/B 16x32 frag order; V uses PV B-frag order):
__device__ __forceinline__ size_t kq_idx(int s, int c) {
    return (size_t)(s >> 4) * 1024 + (size_t)(c >> 5) * 512 +
           (size_t)(((s & 15) | (((c >> 3) & 3) << 4))) * 8 + (c & 7);
}
__device__ __forceinline__ size_t v_idx(int s, int c) {
    return (size_t)(s >> 5) * 2048 + (size_t)(c >> 4) * 512 +
           (size_t)(((c & 15) | (((s >> 3) & 3) << 4))) * 8 + (s & 7);
}

// ---------------- K0a: convert x to fp16 ----------------
__global__ void k_split_x(const float4* __restrict__ x, ushort4* __restrict__ xf, int n4) {
    int i = blockIdx.x * 256 + threadIdx.x;
    if (i >= n4) return;
    float4 v = x[i];
    float f[4] = {v.x, v.y, v.z, v.w};
    ushort4 h;
    u16* hp = (u16*)&h;
#pragma unroll
    for (int j = 0; j < 4; j++) hp[j] = f32_to_f16(f[j]);
    xf[i] = h;
}

// ---------------- K0b: transpose + convert the 4 weight matrices to fp16 ----------------
__global__ void k_split_w(const float* __restrict__ w0, const float* __restrict__ w1,
                          const float* __restrict__ w2, const float* __restrict__ w3,
                          u16* __restrict__ wt) {
    __shared__ float tile[32][33];
    int bx = blockIdx.x;
    int wi = bx >> 10;
    int t  = bx & 1023;
    int kt = t >> 5, nt = t & 31;
    const float* w = (wi == 0) ? w0 : (wi == 1) ? w1 : (wi == 2) ? w2 : w3;
    int tx = threadIdx.x & 31, ty = threadIdx.x >> 5;
#pragma unroll
    for (int i = 0; i < 4; i++) {
        int r = ty + i * 8;
        tile[r][tx] = w[(size_t)(kt * 32 + r) * 1024 + nt * 32 + tx];
    }
    __syncthreads();
    size_t base = ((size_t)wi << 20);
#pragma unroll
    for (int i = 0; i < 4; i++) {
        int r = ty + i * 8;
        size_t dst = base + (size_t)(nt * 32 + r) * 1024 + kt * 32 + tx;
        wt[dst] = f32_to_f16(tile[tx][r]);
    }
}

// ================= m97-style 128x128 GEMM core (unchanged) =================
#define GEMM_KLOOP(Aptr, Bptr, am0, bn0)                                              \
    f32x4 acc[4][4];                                                                   \
    _Pragma("unroll")                                                                  \
    for (int mt = 0; mt < 4; mt++)                                                     \
        _Pragma("unroll")                                                              \
        for (int nt = 0; nt < 4; nt++) acc[mt][nt] = (f32x4)0.f;                       \
    int rowc = lane >> 3;                                                              \
    int slx  = (lane & 7) ^ rowc;   /* pre-swizzled source slot */                     \
    int kx   = slx << 3;                                                               \
    for (int k0 = 0; k0 < 1024; k0 += 64) {                                            \
        _Pragma("unroll")                                                              \
        for (int i = 0; i < 4; i++) {                                                  \
            int c = w * 4 + i;                                                         \
            int row = c * 8 + rowc;                                                    \
            gload_lds16(Aptr + (size_t)(am0 + row) * 1024 + k0 + kx,                   \
                        (char*)As + c * 1024 + lane * 16);                             \
            gload_lds16(Bptr + (size_t)(bn0 + row) * 1024 + k0 + kx,                   \
                        (char*)Bs + c * 1024 + lane * 16);                             \
        }                                                                              \
        __syncthreads();                                                               \
        _Pragma("unroll")                                                              \
        for (int kk = 0; kk < 2; kk++) {                                               \
            short8 af[4], bf[4];                                                       \
            _Pragma("unroll")                                                          \
            for (int mt = 0; mt < 4; mt++) {                                           \
                int row = wr * 64 + mt * 16 + lrow;                                    \
                int slot = (kk * 4 + (lane >> 4)) ^ (row & 7);                         \
                af[mt] = *(const short8*)(As + row * 64 + slot * 8);                   \
            }                                                                          \
            _Pragma("unroll")                                                          \
            for (int nt = 0; nt < 4; nt++) {                                           \
                int row = wc * 64 + nt * 16 + lrow;                                    \
                int slot = (kk * 4 + (lane >> 4)) ^ (row & 7);                         \
                bf[nt] = *(const short8*)(Bs + row * 64 + slot * 8);                   \
            }                                                                          \
            _Pragma("unroll")                                                          \
            for (int mt = 0; mt < 4; mt++)                                             \
                _Pragma("unroll")                                                      \
                for (int nt = 0; nt < 4; nt++)                                         \
                    acc[mt][nt] = __builtin_amdgcn_mfma_f32_16x16x32_f16(              \
                        af[mt], bf[nt], acc[mt][nt], 0, 0, 0);                         \
        }                                                                              \
        __syncthreads();                                                               \
    }

// ---------------- K1: QKV projection GEMM ----------------
__global__ __launch_bounds__(256) void k_gemm_qkv(
    const u16* __restrict__ xf, const u16* __restrict__ wt,
    const float* __restrict__ bq, const float* __restrict__ bk, const float* __restrict__ bv,
    u16* __restrict__ qf, u16* __restrict__ kf, u16* __restrict__ vt) {
    __shared__ u16 As[128 * 64];
    __shared__ u16 Bs[128 * 64];
    int lane = threadIdx.x & 63, w = threadIdx.x >> 6;
    int wr = w >> 1, wc = w & 1;
    int lrow = lane & 15, rbase = (lane >> 4) * 4;
    int lin = blockIdx.y * 24 + blockIdx.x;
    int lin2 = (lin & 7) * 192 + (lin >> 3);
    int bx = lin2 % 24, by = lin2 / 24;
    int am0 = by * 128;
    int n0 = bx * 128;
    int wi = n0 >> 10;
    int nn0 = n0 & 1023;
    const u16* bmat = wt + ((size_t)wi << 20);

    GEMM_KLOOP(xf, bmat, am0, nn0)

    const float* bias = (wi == 0) ? bq : (wi == 1) ? bk : bv;
#pragma unroll
    for (int mt = 0; mt < 4; mt++)
#pragma unroll
        for (int nt = 0; nt < 4; nt++) {
            int n = nn0 + wc * 64 + nt * 16 + lrow;
            float bias_v = bias[n];
            int hh = n >> 6, c = n & 63;
#pragma unroll
            for (int j = 0; j < 4; j++) {
                int m = am0 + wr * 64 + mt * 16 + rbase + j;
                float v = acc[mt][nt][j] + bias_v;
                int b = m >> 11, s = m & 2047;
                size_t hb = (size_t)(b * NH + hh) * HSZ;
                if (wi == 0) {
                    qf[hb + kq_idx(s, c)] = f32_to_f16(v);
                } else if (wi == 1) {
                    kf[hb + kq_idx(s, c)] = f32_to_f16(v);
                } else {
                    vt[hb + v_idx(s, c)] = f32_to_f16(v);
                }
            }
        }
}

// ---------------- K3: output projection GEMM ----------------
__global__ __launch_bounds__(256) void k_gemm_out(
    const u16* __restrict__ af_in, const u16* __restrict__ wt,
    const float* __restrict__ bo, float* __restrict__ out) {
    __shared__ u16 As[128 * 64];
    __shared__ u16 Bs[128 * 64];
    int lane = threadIdx.x & 63, w = threadIdx.x >> 6;
    int wr = w >> 1, wc = w & 1;
    int lrow = lane & 15, rbase = (lane >> 4) * 4;
    int lin = blockIdx.y * 8 + blockIdx.x;
    int lin2 = (lin & 7) * 64 + (lin >> 3);
    int bx = lin2 % 8, by = lin2 / 8;
    int am0 = by * 128;
    int n0 = bx * 128;
    const u16* bmat = wt + ((size_t)3 << 20);

    GEMM_KLOOP(af_in, bmat, am0, n0)

#pragma unroll
    for (int mt = 0; mt < 4; mt++)
#pragma unroll
        for (int nt = 0; nt < 4; nt++) {
            int n = n0 + wc * 64 + nt * 16 + lrow;
            float bias_v = bo[n];
#pragma unroll
            for (int j = 0; j < 4; j++) {
                int m = am0 + wr * 64 + mt * 16 + rbase + j;
                out[(size_t)m * 1024 + n] = acc[mt][nt][j] + bias_v;
            }
        }
}

// ---------------- K2: fused attention (pipelined, small-LDS, NT stores) ----------------
// One wg = one (b,h, 16-row Q tile). 8 waves, each owns 256 K-columns.
// LDS cut to ~29KB (2-pass ctx epilogue) to lift the occupancy ceiling.
#define NW 8
__global__ __launch_bounds__(512, 4) void k_attn(
    const u16* __restrict__ qf, const u16* __restrict__ kf, const u16* __restrict__ vt,
    float* __restrict__ attn_out, u16* __restrict__ cf) {
    __shared__ float2 sm_ms[NW][16];       // (max, sum) per wave per qrow
    __shared__ u16 p_lds[NW][16][40];
    __shared__ float ctx_red[NW][16][36];  // half-width, 2-pass epilogue

    int w = threadIdx.x >> 6, lane = threadIdx.x & 63;
    // XCD-chunked swizzle: 8192 wgs -> 1024/XCD = 8 heads/XCD (K/V L2 reuse)
    int bid0 = blockIdx.x;
    int bid = (bid0 & 7) * 1024 + (bid0 >> 3);
    int qt = bid & 127, bh = bid >> 7;
    int q0 = qt * 16;
    int lrow = lane & 15, lk8 = (lane >> 4) * 8, rbase = (lane >> 4) * 4;

    const u16* qp  = qf + (size_t)bh * HSZ;
    const u16* kfp = kf + (size_t)bh * HSZ;
    const u16* vtp = vt + (size_t)bh * HSZ;

    // Q as B-operand fragments, fragment-tiled: contiguous per wave
    short8 aq[2];
#pragma unroll
    for (int kk = 0; kk < 2; kk++)
        aq[kk] = *(const short8*)(qp + (size_t)qt * 1024 + kk * 512 + lane * 8);

    f32x4 acc[16];
#pragma unroll
    for (int t = 0; t < 16; t++) acc[t] = (f32x4)0.f;

    int c0w = w * 256;
    int tbase = c0w >> 4;   // K tile base for this wave
    const u16* kl = kfp + (size_t)tbase * 1024 + lane * 8;

    // ---- QK^T: depth-4 K-tile register pipeline (8 loads in flight) ----
    short8 kbuf[4][2];
#pragma unroll
    for (int t = 0; t < 4; t++) {
        kbuf[t][0] = *(const short8*)(kl + (size_t)t * 1024);
        kbuf[t][1] = *(const short8*)(kl + (size_t)t * 1024 + 512);
    }
#pragma unroll
    for (int t = 0; t < 16; t++) {
        short8 b0 = kbuf[t & 3][0];
        short8 b1 = kbuf[t & 3][1];
        if (t < 12) {
            kbuf[t & 3][0] = *(const short8*)(kl + (size_t)(t + 4) * 1024);
            kbuf[t & 3][1] = *(const short8*)(kl + (size_t)(t + 4) * 1024 + 512);
        }
        __builtin_amdgcn_s_setprio(1);
        acc[t] = __builtin_amdgcn_mfma_f32_16x16x32_f16(b0, aq[0], acc[t], 0, 0, 0);
        acc[t] = __builtin_amdgcn_mfma_f32_16x16x32_f16(b1, aq[1], acc[t], 0, 0, 0);
        __builtin_amdgcn_s_setprio(0);
    }

    // ---- V issue-early: first c2-group's loads hide under softmax ----
    int cbase = c0w >> 5;   // V tile base for this wave
    const u16* vl = vtp + (size_t)cbase * 2048 + lane * 8;
    short8 vbuf[2][4];
#pragma unroll
    for (int nt = 0; nt < 4; nt++) vbuf[0][nt] = *(const short8*)(vl + nt * 512);

    // ---- softmax: in-lane reduction + single barrier ----
    float m0_ = acc[0][0], m1_ = acc[0][1], m2_ = acc[0][2], m3_ = acc[0][3];
#pragma unroll
    for (int t = 1; t < 16; t++) {
        m0_ = fmaxf(m0_, acc[t][0]);
        m1_ = fmaxf(m1_, acc[t][1]);
        m2_ = fmaxf(m2_, acc[t][2]);
        m3_ = fmaxf(m3_, acc[t][3]);
    }
    float mv = fmaxf(fmaxf(m0_, m1_), fmaxf(m2_, m3_));
    mv = fmaxf(mv, __shfl_xor(mv, 16, 64));
    mv = fmaxf(mv, __shfl_xor(mv, 32, 64));   // wave-local row max

    const float C = 0.125f * 1.44269504088896f;
    float s0_ = 0.f, s1_ = 0.f, s2_ = 0.f, s3_ = 0.f;
#pragma unroll
    for (int t = 0; t < 16; t++) {
        float e0 = exp2f((acc[t][0] - mv) * C);
        float e1 = exp2f((acc[t][1] - mv) * C);
        float e2 = exp2f((acc[t][2] - mv) * C);
        float e3 = exp2f((acc[t][3] - mv) * C);
        acc[t][0] = e0; acc[t][1] = e1; acc[t][2] = e2; acc[t][3] = e3;
        s0_ += e0; s1_ += e1; s2_ += e2; s3_ += e3;
    }
    float sv = (s0_ + s1_) + (s2_ + s3_);
    sv += __shfl_xor(sv, 16, 64);
    sv += __shfl_xor(sv, 32, 64);             // wave-local row sum

    if (lane < 16) sm_ms[w][lrow] = make_float2(mv, sv);
    __syncthreads();                          // ONE barrier for softmax exchange

    float M = sm_ms[0][lrow].x;
#pragma unroll
    for (int w2 = 1; w2 < NW; w2++) M = fmaxf(M, sm_ms[w2][lrow].x);
    float L = 0.f;
#pragma unroll
    for (int w2 = 0; w2 < NW; w2++) {
        float2 ms = sm_ms[w2][lrow];
        L += ms.y * exp2f((ms.x - M) * C);
    }
    float scale = exp2f((mv - M) * C) / L;

    // ---- PV + embedded normalize + NT attn store, V depth-2 prefetch ----
    float* attn_row = attn_out + ((size_t)bh * SEQ + q0 + lrow) * SEQ + c0w + rbase;
    f32x4 cacc[4];
#pragma unroll
    for (int nt = 0; nt < 4; nt++) cacc[nt] = (f32x4)0.f;
#pragma unroll
    for (int c2 = 0; c2 < 8; c2++) {
        if (c2 < 7) {
#pragma unroll
            for (int nt = 0; nt < 4; nt++)
                vbuf[(c2 + 1) & 1][nt] =
                    *(const short8*)(vl + (size_t)(c2 + 1) * 2048 + nt * 512);
        }
#pragma unroll
        for (int tt = 0; tt < 2; tt++) {
            int t = c2 * 2 + tt;
            f32x4 pv;
            pv[0] = acc[t][0] * scale; pv[1] = acc[t][1] * scale;
            pv[2] = acc[t][2] * scale; pv[3] = acc[t][3] * scale;
            __builtin_nontemporal_store(pv, (f32x4*)(attn_row + t * 16));
            ushort4 pk;
            pk.x = f32_to_f16(pv[0]); pk.y = f32_to_f16(pv[1]);
            pk.z = f32_to_f16(pv[2]); pk.w = f32_to_f16(pv[3]);
            *(ushort4*)&p_lds[w][lrow][tt * 16 + rbase] = pk;
        }
        short8 pf = *(const short8*)&p_lds[w][lrow][lk8];
        __builtin_amdgcn_s_setprio(1);
#pragma unroll
        for (int nt = 0; nt < 4; nt++)
            cacc[nt] = __builtin_amdgcn_mfma_f32_16x16x32_f16(pf, vbuf[c2 & 1][nt], cacc[nt], 0, 0, 0);
        __builtin_amdgcn_s_setprio(0);
    }

    // ---- 2-pass cross-wave ctx reduce (half-width LDS) + write ctx fp16 ----
    int b = bh >> 4, h = bh & 15;
    int rr = threadIdx.x >> 5, cc = threadIdx.x & 31;   // 512 threads = 16 x 32
#pragma unroll
    for (int half = 0; half < 2; half++) {
        __syncthreads();   // protect ctx_red reuse (and after p_lds use)
#pragma unroll
        for (int nt2 = 0; nt2 < 2; nt2++)
#pragma unroll
            for (int j = 0; j < 4; j++)
                ctx_red[w][rbase + j][nt2 * 16 + lrow] = cacc[half * 2 + nt2][j];
        __syncthreads();
        float s = 0.f;
#pragma unroll
        for (int w2 = 0; w2 < NW; w2++) s += ctx_red[w2][rr][cc];
        size_t idx = ((size_t)b * SEQ + q0 + rr) * DM + h * HD + half * 32 + cc;
        cf[idx] = f32_to_f16(s);
    }
}

extern "C" void kernel_launch(void* const* d_in, const int* in_sizes, int n_in,
                              void* d_out, int out_size, void* d_ws, size_t ws_size,
                              hipStream_t stream) {
    const float* x  = (const float*)d_in[0];
    const float* wq = (const float*)d_in[1];
    const float* bq = (const float*)d_in[2];
    const float* wk = (const float*)d_in[3];
    const float* bk = (const float*)d_in[4];
    const float* wv = (const float*)d_in[5];
    const float* bv = (const float*)d_in[6];
    const float* wo = (const float*)d_in[7];
    const float* bo = (const float*)d_in[8];

    float* out  = (float*)d_out;
    float* attn = out + (size_t)BATCH * SEQ * DM;

    char* ws = (char*)d_ws;
    const size_t MB = 1u << 20;
    u16* x16  = (u16*)(ws + 0 * MB);    // 16 MiB
    u16* wt16 = (u16*)(ws + 16 * MB);   // 8 MiB (4 weights, [n][k], fp16)
    u16* qf   = (u16*)(ws + 24 * MB);   // 16 MiB (fragment-tiled)
    u16* kf   = (u16*)(ws + 40 * MB);   // 16 MiB (fragment-tiled)
    u16* vt   = (u16*)(ws + 56 * MB);   // 16 MiB (fragment-tiled)
    u16* cf   = (u16*)(ws + 72 * MB);   // 16 MiB

    int n4 = BATCH * SEQ * DM / 4;
    k_split_x<<<(n4 + 255) / 256, 256, 0, stream>>>((const float4*)x, (ushort4*)x16, n4);
    k_split_w<<<4096, 256, 0, stream>>>(wq, wk, wv, wo, wt16);
    k_gemm_qkv<<<dim3(24, 64), 256, 0, stream>>>(x16, wt16, bq, bk, bv, qf, kf, vt);
    k_attn<<<BATCH * NH * (SEQ / 16), 512, 0, stream>>>(qf, kf, vt, attn, cf);
    k_gemm_out<<<dim3(8, 64), 256, 0, stream>>>(cf, wt16, bo, out);
}

// Round 12
// 380.344 us; speedup vs baseline: 2.0321x; 1.1444x over previous
//
#include <hip/hip_runtime.h>
#include <hip/hip_bf16.h>
#include <stdint.h>

typedef __attribute__((ext_vector_type(8))) short short8;
typedef __attribute__((ext_vector_type(4))) float f32x4;
typedef unsigned short u16;

#define BATCH 4
#define NH    16
#define SEQ   2048
#define DM    1024
#define HD    64
#define HSZ   131072   // SEQ*HD, u16 elems per head

__device__ __forceinline__ u16 f32_to_f16(float f) {
    _Float16 h = (_Float16)f;
    return __builtin_bit_cast(unsigned short, h);
}
__device__ __forceinline__ float f16_to_f32(u16 u) {
    _Float16 h = __builtin_bit_cast(_Float16, u);
    return (float)h;
}

__device__ __forceinline__ void gload_lds16(const void* g, void* l) {
    __builtin_amdgcn_global_load_lds(
        (const __attribute__((address_space(1))) void*)g,
        (__attribute__((address_space(3))) void*)l, 16, 0, 0);
}

// Fragment-tiled indices (K/Q use A/B 16x32 frag order; V uses PV B-frag order):
__device__ __forceinline__ size_t kq_idx(int s, int c) {
    return (size_t)(s >> 4) * 1024 + (size_t)(c >> 5) * 512 +
           (size_t)(((s & 15) | (((c >> 3) & 3) << 4))) * 8 + (c & 7);
}
__device__ __forceinline__ size_t v_idx(int s, int c) {
    return (size_t)(s >> 5) * 2048 + (size_t)(c >> 4) * 512 +
           (size_t)(((c & 15) | (((s >> 3) & 3) << 4))) * 8 + (s & 7);
}

// ---------------- K0a: convert x to fp16 ----------------
__global__ void k_split_x(const float4* __restrict__ x, ushort4* __restrict__ xf, int n4) {
    int i = blockIdx.x * 256 + threadIdx.x;
    if (i >= n4) return;
    float4 v = x[i];
    float f[4] = {v.x, v.y, v.z, v.w};
    ushort4 h;
    u16* hp = (u16*)&h;
#pragma unroll
    for (int j = 0; j < 4; j++) hp[j] = f32_to_f16(f[j]);
    xf[i] = h;
}

// ---------------- K0b: transpose + convert the 4 weight matrices to fp16 ----------------
__global__ void k_split_w(const float* __restrict__ w0, const float* __restrict__ w1,
                          const float* __restrict__ w2, const float* __restrict__ w3,
                          u16* __restrict__ wt) {
    __shared__ float tile[32][33];
    int bx = blockIdx.x;
    int wi = bx >> 10;
    int t  = bx & 1023;
    int kt = t >> 5, nt = t & 31;
    const float* w = (wi == 0) ? w0 : (wi == 1) ? w1 : (wi == 2) ? w2 : w3;
    int tx = threadIdx.x & 31, ty = threadIdx.x >> 5;
#pragma unroll
    for (int i = 0; i < 4; i++) {
        int r = ty + i * 8;
        tile[r][tx] = w[(size_t)(kt * 32 + r) * 1024 + nt * 32 + tx];
    }
    __syncthreads();
    size_t base = ((size_t)wi << 20);
#pragma unroll
    for (int i = 0; i < 4; i++) {
        int r = ty + i * 8;
        size_t dst = base + (size_t)(nt * 32 + r) * 1024 + kt * 32 + tx;
        wt[dst] = f32_to_f16(tile[tx][r]);
    }
}

// ================= m97-style 128x128 GEMM core (unchanged) =================
#define GEMM_KLOOP(Aptr, Bptr, am0, bn0)                                              \
    f32x4 acc[4][4];                                                                   \
    _Pragma("unroll")                                                                  \
    for (int mt = 0; mt < 4; mt++)                                                     \
        _Pragma("unroll")                                                              \
        for (int nt = 0; nt < 4; nt++) acc[mt][nt] = (f32x4)0.f;                       \
    int rowc = lane >> 3;                                                              \
    int slx  = (lane & 7) ^ rowc;   /* pre-swizzled source slot */                     \
    int kx   = slx << 3;                                                               \
    for (int k0 = 0; k0 < 1024; k0 += 64) {                                            \
        _Pragma("unroll")                                                              \
        for (int i = 0; i < 4; i++) {                                                  \
            int c = w * 4 + i;                                                         \
            int row = c * 8 + rowc;                                                    \
            gload_lds16(Aptr + (size_t)(am0 + row) * 1024 + k0 + kx,                   \
                        (char*)As + c * 1024 + lane * 16);                             \
            gload_lds16(Bptr + (size_t)(bn0 + row) * 1024 + k0 + kx,                   \
                        (char*)Bs + c * 1024 + lane * 16);                             \
        }                                                                              \
        __syncthreads();                                                               \
        _Pragma("unroll")                                                              \
        for (int kk = 0; kk < 2; kk++) {                                               \
            short8 af[4], bf[4];                                                       \
            _Pragma("unroll")                                                          \
            for (int mt = 0; mt < 4; mt++) {                                           \
                int row = wr * 64 + mt * 16 + lrow;                                    \
                int slot = (kk * 4 + (lane >> 4)) ^ (row & 7);                         \
                af[mt] = *(const short8*)(As + row * 64 + slot * 8);                   \
            }                                                                          \
            _Pragma("unroll")                                                          \
            for (int nt = 0; nt < 4; nt++) {                                           \
                int row = wc * 64 + nt * 16 + lrow;                                    \
                int slot = (kk * 4 + (lane >> 4)) ^ (row & 7);                         \
                bf[nt] = *(const short8*)(Bs + row * 64 + slot * 8);                   \
            }                                                                          \
            _Pragma("unroll")                                                          \
            for (int mt = 0; mt < 4; mt++)                                             \
                _Pragma("unroll")                                                      \
                for (int nt = 0; nt < 4; nt++)                                         \
                    acc[mt][nt] = __builtin_amdgcn_mfma_f32_16x16x32_f16(              \
                        af[mt], bf[nt], acc[mt][nt], 0, 0, 0);                         \
        }                                                                              \
        __syncthreads();                                                               \
    }

// ---------------- K1: QKV projection GEMM ----------------
__global__ __launch_bounds__(256) void k_gemm_qkv(
    const u16* __restrict__ xf, const u16* __restrict__ wt,
    const float* __restrict__ bq, const float* __restrict__ bk, const float* __restrict__ bv,
    u16* __restrict__ qf, u16* __restrict__ kf, u16* __restrict__ vt) {
    __shared__ u16 As[128 * 64];
    __shared__ u16 Bs[128 * 64];
    int lane = threadIdx.x & 63, w = threadIdx.x >> 6;
    int wr = w >> 1, wc = w & 1;
    int lrow = lane & 15, rbase = (lane >> 4) * 4;
    int lin = blockIdx.y * 24 + blockIdx.x;
    int lin2 = (lin & 7) * 192 + (lin >> 3);
    int bx = lin2 % 24, by = lin2 / 24;
    int am0 = by * 128;
    int n0 = bx * 128;
    int wi = n0 >> 10;
    int nn0 = n0 & 1023;
    const u16* bmat = wt + ((size_t)wi << 20);

    GEMM_KLOOP(xf, bmat, am0, nn0)

    const float* bias = (wi == 0) ? bq : (wi == 1) ? bk : bv;
#pragma unroll
    for (int mt = 0; mt < 4; mt++)
#pragma unroll
        for (int nt = 0; nt < 4; nt++) {
            int n = nn0 + wc * 64 + nt * 16 + lrow;
            float bias_v = bias[n];
            int hh = n >> 6, c = n & 63;
#pragma unroll
            for (int j = 0; j < 4; j++) {
                int m = am0 + wr * 64 + mt * 16 + rbase + j;
                float v = acc[mt][nt][j] + bias_v;
                int b = m >> 11, s = m & 2047;
                size_t hb = (size_t)(b * NH + hh) * HSZ;
                if (wi == 0) {
                    qf[hb + kq_idx(s, c)] = f32_to_f16(v);
                } else if (wi == 1) {
                    kf[hb + kq_idx(s, c)] = f32_to_f16(v);
                } else {
                    vt[hb + v_idx(s, c)] = f32_to_f16(v);
                }
            }
        }
}

// ---------------- K3: output projection GEMM ----------------
__global__ __launch_bounds__(256) void k_gemm_out(
    const u16* __restrict__ af_in, const u16* __restrict__ wt,
    const float* __restrict__ bo, float* __restrict__ out) {
    __shared__ u16 As[128 * 64];
    __shared__ u16 Bs[128 * 64];
    int lane = threadIdx.x & 63, w = threadIdx.x >> 6;
    int wr = w >> 1, wc = w & 1;
    int lrow = lane & 15, rbase = (lane >> 4) * 4;
    int lin = blockIdx.y * 8 + blockIdx.x;
    int lin2 = (lin & 7) * 64 + (lin >> 3);
    int bx = lin2 % 8, by = lin2 / 8;
    int am0 = by * 128;
    int n0 = bx * 128;
    const u16* bmat = wt + ((size_t)3 << 20);

    GEMM_KLOOP(af_in, bmat, am0, n0)

#pragma unroll
    for (int mt = 0; mt < 4; mt++)
#pragma unroll
        for (int nt = 0; nt < 4; nt++) {
            int n = n0 + wc * 64 + nt * 16 + lrow;
            float bias_v = bo[n];
#pragma unroll
            for (int j = 0; j < 4; j++) {
                int m = am0 + wr * 64 + mt * 16 + rbase + j;
                out[(size_t)m * 1024 + n] = acc[mt][nt][j] + bias_v;
            }
        }
}

// ---------------- K2: fused attention (pipelined + full-line NT attn stores) ----------------
// One wg = one (b,h, 16-row Q tile). 8 waves, each owns 256 K-columns.
// P-tile staged f32 in XOR-swizzled LDS; attn stores are 8 rows x 128B full lines.
#define NW 8
__global__ __launch_bounds__(512, 4) void k_attn(
    const u16* __restrict__ qf, const u16* __restrict__ kf, const u16* __restrict__ vt,
    float* __restrict__ attn_out, u16* __restrict__ cf) {
    __shared__ float2 sm_ms[NW][16];       // (max, sum) per wave per qrow
    __shared__ float pt[NW][16][32];       // f32 P tile, slot-swizzled (slot ^= row&7)
    __shared__ float ctx_red[NW][16][36];  // half-width, 2-pass epilogue

    int w = threadIdx.x >> 6, lane = threadIdx.x & 63;
    // XCD-chunked swizzle: 8192 wgs -> 1024/XCD = 8 heads/XCD (K/V L2 reuse)
    int bid0 = blockIdx.x;
    int bid = (bid0 & 7) * 1024 + (bid0 >> 3);
    int qt = bid & 127, bh = bid >> 7;
    int q0 = qt * 16;
    int lrow = lane & 15, rbase = (lane >> 4) * 4;
    int g = lane >> 4;

    const u16* qp  = qf + (size_t)bh * HSZ;
    const u16* kfp = kf + (size_t)bh * HSZ;
    const u16* vtp = vt + (size_t)bh * HSZ;

    // Q as B-operand fragments, fragment-tiled: contiguous per wave
    short8 aq[2];
#pragma unroll
    for (int kk = 0; kk < 2; kk++)
        aq[kk] = *(const short8*)(qp + (size_t)qt * 1024 + kk * 512 + lane * 8);

    f32x4 acc[16];
#pragma unroll
    for (int t = 0; t < 16; t++) acc[t] = (f32x4)0.f;

    int c0w = w * 256;
    int tbase = c0w >> 4;   // K tile base for this wave
    const u16* kl = kfp + (size_t)tbase * 1024 + lane * 8;

    // ---- QK^T: depth-4 K-tile register pipeline (8 loads in flight) ----
    short8 kbuf[4][2];
#pragma unroll
    for (int t = 0; t < 4; t++) {
        kbuf[t][0] = *(const short8*)(kl + (size_t)t * 1024);
        kbuf[t][1] = *(const short8*)(kl + (size_t)t * 1024 + 512);
    }
#pragma unroll
    for (int t = 0; t < 16; t++) {
        short8 b0 = kbuf[t & 3][0];
        short8 b1 = kbuf[t & 3][1];
        if (t < 12) {
            kbuf[t & 3][0] = *(const short8*)(kl + (size_t)(t + 4) * 1024);
            kbuf[t & 3][1] = *(const short8*)(kl + (size_t)(t + 4) * 1024 + 512);
        }
        __builtin_amdgcn_s_setprio(1);
        acc[t] = __builtin_amdgcn_mfma_f32_16x16x32_f16(b0, aq[0], acc[t], 0, 0, 0);
        acc[t] = __builtin_amdgcn_mfma_f32_16x16x32_f16(b1, aq[1], acc[t], 0, 0, 0);
        __builtin_amdgcn_s_setprio(0);
    }

    // ---- V issue-early: first c2-group's loads hide under softmax ----
    int cbase = c0w >> 5;   // V tile base for this wave
    const u16* vl = vtp + (size_t)cbase * 2048 + lane * 8;
    short8 vbuf[2][4];
#pragma unroll
    for (int nt = 0; nt < 4; nt++) vbuf[0][nt] = *(const short8*)(vl + nt * 512);

    // ---- softmax: in-lane reduction + single barrier ----
    float m0_ = acc[0][0], m1_ = acc[0][1], m2_ = acc[0][2], m3_ = acc[0][3];
#pragma unroll
    for (int t = 1; t < 16; t++) {
        m0_ = fmaxf(m0_, acc[t][0]);
        m1_ = fmaxf(m1_, acc[t][1]);
        m2_ = fmaxf(m2_, acc[t][2]);
        m3_ = fmaxf(m3_, acc[t][3]);
    }
    float mv = fmaxf(fmaxf(m0_, m1_), fmaxf(m2_, m3_));
    mv = fmaxf(mv, __shfl_xor(mv, 16, 64));
    mv = fmaxf(mv, __shfl_xor(mv, 32, 64));   // wave-local row max

    const float C = 0.125f * 1.44269504088896f;
    float s0_ = 0.f, s1_ = 0.f, s2_ = 0.f, s3_ = 0.f;
#pragma unroll
    for (int t = 0; t < 16; t++) {
        float e0 = exp2f((acc[t][0] - mv) * C);
        float e1 = exp2f((acc[t][1] - mv) * C);
        float e2 = exp2f((acc[t][2] - mv) * C);
        float e3 = exp2f((acc[t][3] - mv) * C);
        acc[t][0] = e0; acc[t][1] = e1; acc[t][2] = e2; acc[t][3] = e3;
        s0_ += e0; s1_ += e1; s2_ += e2; s3_ += e3;
    }
    float sv = (s0_ + s1_) + (s2_ + s3_);
    sv += __shfl_xor(sv, 16, 64);
    sv += __shfl_xor(sv, 32, 64);             // wave-local row sum

    if (lane < 16) sm_ms[w][lrow] = make_float2(mv, sv);
    __syncthreads();                          // ONE barrier for softmax exchange

    float M = sm_ms[0][lrow].x;
#pragma unroll
    for (int w2 = 1; w2 < NW; w2++) M = fmaxf(M, sm_ms[w2][lrow].x);
    float L = 0.f;
#pragma unroll
    for (int w2 = 0; w2 < NW; w2++) {
        float2 ms = sm_ms[w2][lrow];
        L += ms.y * exp2f((ms.x - M) * C);
    }
    float scale = exp2f((mv - M) * C) / L;

    // ---- PV + full-line NT attn stores via swizzled f32 LDS tile ----
    int srow = lane >> 3, sslot = lane & 7;   // store lane map: 8 rows x 128B lines
    f32x4 cacc[4];
#pragma unroll
    for (int nt = 0; nt < 4; nt++) cacc[nt] = (f32x4)0.f;
#pragma unroll
    for (int c2 = 0; c2 < 8; c2++) {
        if (c2 < 7) {
#pragma unroll
            for (int nt = 0; nt < 4; nt++)
                vbuf[(c2 + 1) & 1][nt] =
                    *(const short8*)(vl + (size_t)(c2 + 1) * 2048 + nt * 512);
        }
        // scale + stage f32 P[16][32] into swizzled LDS (conflict-free b128)
#pragma unroll
        for (int tt = 0; tt < 2; tt++) {
            int t = c2 * 2 + tt;
            f32x4 pv;
            pv[0] = acc[t][0] * scale; pv[1] = acc[t][1] * scale;
            pv[2] = acc[t][2] * scale; pv[3] = acc[t][3] * scale;
            int sl = (tt * 4 + g) ^ (lrow & 7);
            *(f32x4*)&pt[w][lrow][sl * 4] = pv;
        }
        // assemble pf (fp16 A-frag: row=qrow, k=kcol) from LDS
        f32x4 plo = *(const f32x4*)&pt[w][lrow][((2 * g) ^ (lrow & 7)) * 4];
        f32x4 phi = *(const f32x4*)&pt[w][lrow][((2 * g + 1) ^ (lrow & 7)) * 4];
        short8 pf;
        u16* pfp = (u16*)&pf;
#pragma unroll
        for (int j = 0; j < 4; j++) {
            pfp[j]     = f32_to_f16(plo[j]);
            pfp[4 + j] = f32_to_f16(phi[j]);
        }
        __builtin_amdgcn_s_setprio(1);
#pragma unroll
        for (int nt = 0; nt < 4; nt++)
            cacc[nt] = __builtin_amdgcn_mfma_f32_16x16x32_f16(pf, vbuf[c2 & 1][nt], cacc[nt], 0, 0, 0);
        __builtin_amdgcn_s_setprio(0);
        // full-line NT stores: 2 instructions x (8 rows x 128B)
#pragma unroll
        for (int half = 0; half < 2; half++) {
            int r = half * 8 + srow;
            f32x4 vv = *(const f32x4*)&pt[w][r][(sslot ^ (r & 7)) * 4];
            float* dst = attn_out + ((size_t)bh * SEQ + q0 + r) * SEQ + c0w + c2 * 32 + sslot * 4;
            __builtin_nontemporal_store(vv, (f32x4*)dst);
        }
    }

    // ---- 2-pass cross-wave ctx reduce (half-width LDS) + write ctx fp16 ----
    int b = bh >> 4, h = bh & 15;
    int rr = threadIdx.x >> 5, cc = threadIdx.x & 31;   // 512 threads = 16 x 32
#pragma unroll
    for (int half = 0; half < 2; half++) {
        __syncthreads();   // protect ctx_red reuse
#pragma unroll
        for (int nt2 = 0; nt2 < 2; nt2++)
#pragma unroll
            for (int j = 0; j < 4; j++)
                ctx_red[w][rbase + j][nt2 * 16 + lrow] = cacc[half * 2 + nt2][j];
        __syncthreads();
        float s = 0.f;
#pragma unroll
        for (int w2 = 0; w2 < NW; w2++) s += ctx_red[w2][rr][cc];
        size_t idx = ((size_t)b * SEQ + q0 + rr) * DM + h * HD + half * 32 + cc;
        cf[idx] = f32_to_f16(s);
    }
}

extern "C" void kernel_launch(void* const* d_in, const int* in_sizes, int n_in,
                              void* d_out, int out_size, void* d_ws, size_t ws_size,
                              hipStream_t stream) {
    const float* x  = (const float*)d_in[0];
    const float* wq = (const float*)d_in[1];
    const float* bq = (const float*)d_in[2];
    const float* wk = (const float*)d_in[3];
    const float* bk = (const float*)d_in[4];
    const float* wv = (const float*)d_in[5];
    const float* bv = (const float*)d_in[6];
    const float* wo = (const float*)d_in[7];
    const float* bo = (const float*)d_in[8];

    float* out  = (float*)d_out;
    float* attn = out + (size_t)BATCH * SEQ * DM;

    char* ws = (char*)d_ws;
    const size_t MB = 1u << 20;
    u16* x16  = (u16*)(ws + 0 * MB);    // 16 MiB
    u16* wt16 = (u16*)(ws + 16 * MB);   // 8 MiB (4 weights, [n][k], fp16)
    u16* qf   = (u16*)(ws + 24 * MB);   // 16 MiB (fragment-tiled)
    u16* kf   = (u16*)(ws + 40 * MB);   // 16 MiB (fragment-tiled)
    u16* vt   = (u16*)(ws + 56 * MB);   // 16 MiB (fragment-tiled)
    u16* cf   = (u16*)(ws + 72 * MB);   // 16 MiB

    int n4 = BATCH * SEQ * DM / 4;
    k_split_x<<<(n4 + 255) / 256, 256, 0, stream>>>((const float4*)x, (ushort4*)x16, n4);
    k_split_w<<<4096, 256, 0, stream>>>(wq, wk, wv, wo, wt16);
    k_gemm_qkv<<<dim3(24, 64), 256, 0, stream>>>(x16, wt16, bq, bk, bv, qf, kf, vt);
    k_attn<<<BATCH * NH * (SEQ / 16), 512, 0, stream>>>(qf, kf, vt, attn, cf);
    k_gemm_out<<<dim3(8, 64), 256, 0, stream>>>(cf, wt16, bo, out);
}

// Round 13
// 379.891 us; speedup vs baseline: 2.0345x; 1.0012x over previous
//
#include <hip/hip_runtime.h>
#include <hip/hip_bf16.h>
#include <stdint.h>

typedef __attribute__((ext_vector_type(8))) short short8;
typedef __attribute__((ext_vector_type(4))) float f32x4;
typedef unsigned short u16;

#define BATCH 4
#define NH    16
#define SEQ   2048
#define DM    1024
#define HD    64
#define HSZ   131072   // SEQ*HD, u16 elems per head

__device__ __forceinline__ u16 f32_to_f16(float f) {
    _Float16 h = (_Float16)f;
    return __builtin_bit_cast(unsigned short, h);
}
__device__ __forceinline__ float f16_to_f32(u16 u) {
    _Float16 h = __builtin_bit_cast(_Float16, u);
    return (float)h;
}

__device__ __forceinline__ void gload_lds16(const void* g, void* l) {
    __builtin_amdgcn_global_load_lds(
        (const __attribute__((address_space(1))) void*)g,
        (__attribute__((address_space(3))) void*)l, 16, 0, 0);
}

// Fragment-tiled indices (K/Q use A/B 16x32 frag order; V uses PV B-frag order):
__device__ __forceinline__ size_t kq_idx(int s, int c) {
    return (size_t)(s >> 4) * 1024 + (size_t)(c >> 5) * 512 +
           (size_t)(((s & 15) | (((c >> 3) & 3) << 4))) * 8 + (c & 7);
}
__device__ __forceinline__ size_t v_idx(int s, int c) {
    return (size_t)(s >> 5) * 2048 + (size_t)(c >> 4) * 512 +
           (size_t)(((c & 15) | (((s >> 3) & 3) << 4))) * 8 + (s & 7);
}

// ---------------- K0a: convert x to fp16 ----------------
__global__ void k_split_x(const float4* __restrict__ x, ushort4* __restrict__ xf, int n4) {
    int i = blockIdx.x * 256 + threadIdx.x;
    if (i >= n4) return;
    float4 v = x[i];
    float f[4] = {v.x, v.y, v.z, v.w};
    ushort4 h;
    u16* hp = (u16*)&h;
#pragma unroll
    for (int j = 0; j < 4; j++) hp[j] = f32_to_f16(f[j]);
    xf[i] = h;
}

// ---------------- K0b: transpose + convert the 4 weight matrices to fp16 ----------------
__global__ void k_split_w(const float* __restrict__ w0, const float* __restrict__ w1,
                          const float* __restrict__ w2, const float* __restrict__ w3,
                          u16* __restrict__ wt) {
    __shared__ float tile[32][33];
    int bx = blockIdx.x;
    int wi = bx >> 10;
    int t  = bx & 1023;
    int kt = t >> 5, nt = t & 31;
    const float* w = (wi == 0) ? w0 : (wi == 1) ? w1 : (wi == 2) ? w2 : w3;
    int tx = threadIdx.x & 31, ty = threadIdx.x >> 5;
#pragma unroll
    for (int i = 0; i < 4; i++) {
        int r = ty + i * 8;
        tile[r][tx] = w[(size_t)(kt * 32 + r) * 1024 + nt * 32 + tx];
    }
    __syncthreads();
    size_t base = ((size_t)wi << 20);
#pragma unroll
    for (int i = 0; i < 4; i++) {
        int r = ty + i * 8;
        size_t dst = base + (size_t)(nt * 32 + r) * 1024 + kt * 32 + tx;
        wt[dst] = f32_to_f16(tile[tx][r]);
    }
}

// ================= m97-style 128x128 GEMM core (unchanged) =================
#define GEMM_KLOOP(Aptr, Bptr, am0, bn0)                                              \
    f32x4 acc[4][4];                                                                   \
    _Pragma("unroll")                                                                  \
    for (int mt = 0; mt < 4; mt++)                                                     \
        _Pragma("unroll")                                                              \
        for (int nt = 0; nt < 4; nt++) acc[mt][nt] = (f32x4)0.f;                       \
    int rowc = lane >> 3;                                                              \
    int slx  = (lane & 7) ^ rowc;   /* pre-swizzled source slot */                     \
    int kx   = slx << 3;                                                               \
    for (int k0 = 0; k0 < 1024; k0 += 64) {                                            \
        _Pragma("unroll")                                                              \
        for (int i = 0; i < 4; i++) {                                                  \
            int c = w * 4 + i;                                                         \
            int row = c * 8 + rowc;                                                    \
            gload_lds16(Aptr + (size_t)(am0 + row) * 1024 + k0 + kx,                   \
                        (char*)As + c * 1024 + lane * 16);                             \
            gload_lds16(Bptr + (size_t)(bn0 + row) * 1024 + k0 + kx,                   \
                        (char*)Bs + c * 1024 + lane * 16);                             \
        }                                                                              \
        __syncthreads();                                                               \
        _Pragma("unroll")                                                              \
        for (int kk = 0; kk < 2; kk++) {                                               \
            short8 af[4], bf[4];                                                       \
            _Pragma("unroll")                                                          \
            for (int mt = 0; mt < 4; mt++) {                                           \
                int row = wr * 64 + mt * 16 + lrow;                                    \
                int slot = (kk * 4 + (lane >> 4)) ^ (row & 7);                         \
                af[mt] = *(const short8*)(As + row * 64 + slot * 8);                   \
            }                                                                          \
            _Pragma("unroll")                                                          \
            for (int nt = 0; nt < 4; nt++) {                                           \
                int row = wc * 64 + nt * 16 + lrow;                                    \
                int slot = (kk * 4 + (lane >> 4)) ^ (row & 7);                         \
                bf[nt] = *(const short8*)(Bs + row * 64 + slot * 8);                   \
            }                                                                          \
            _Pragma("unroll")                                                          \
            for (int mt = 0; mt < 4; mt++)                                             \
                _Pragma("unroll")                                                      \
                for (int nt = 0; nt < 4; nt++)                                         \
                    acc[mt][nt] = __builtin_amdgcn_mfma_f32_16x16x32_f16(              \
                        af[mt], bf[nt], acc[mt][nt], 0, 0, 0);                         \
        }                                                                              \
        __syncthreads();                                                               \
    }

// ---------------- K1: QKV projection GEMM ----------------
__global__ __launch_bounds__(256) void k_gemm_qkv(
    const u16* __restrict__ xf, const u16* __restrict__ wt,
    const float* __restrict__ bq, const float* __restrict__ bk, const float* __restrict__ bv,
    u16* __restrict__ qf, u16* __restrict__ kf, u16* __restrict__ vt) {
    __shared__ u16 As[128 * 64];
    __shared__ u16 Bs[128 * 64];
    int lane = threadIdx.x & 63, w = threadIdx.x >> 6;
    int wr = w >> 1, wc = w & 1;
    int lrow = lane & 15, rbase = (lane >> 4) * 4;
    int lin = blockIdx.y * 24 + blockIdx.x;
    int lin2 = (lin & 7) * 192 + (lin >> 3);
    int bx = lin2 % 24, by = lin2 / 24;
    int am0 = by * 128;
    int n0 = bx * 128;
    int wi = n0 >> 10;
    int nn0 = n0 & 1023;
    const u16* bmat = wt + ((size_t)wi << 20);

    GEMM_KLOOP(xf, bmat, am0, nn0)

    const float* bias = (wi == 0) ? bq : (wi == 1) ? bk : bv;
#pragma unroll
    for (int mt = 0; mt < 4; mt++)
#pragma unroll
        for (int nt = 0; nt < 4; nt++) {
            int n = nn0 + wc * 64 + nt * 16 + lrow;
            float bias_v = bias[n];
            int hh = n >> 6, c = n & 63;
#pragma unroll
            for (int j = 0; j < 4; j++) {
                int m = am0 + wr * 64 + mt * 16 + rbase + j;
                float v = acc[mt][nt][j] + bias_v;
                int b = m >> 11, s = m & 2047;
                size_t hb = (size_t)(b * NH + hh) * HSZ;
                if (wi == 0) {
                    qf[hb + kq_idx(s, c)] = f32_to_f16(v);
                } else if (wi == 1) {
                    kf[hb + kq_idx(s, c)] = f32_to_f16(v);
                } else {
                    vt[hb + v_idx(s, c)] = f32_to_f16(v);
                }
            }
        }
}

// ---------------- K3: output projection GEMM ----------------
__global__ __launch_bounds__(256) void k_gemm_out(
    const u16* __restrict__ af_in, const u16* __restrict__ wt,
    const float* __restrict__ bo, float* __restrict__ out) {
    __shared__ u16 As[128 * 64];
    __shared__ u16 Bs[128 * 64];
    int lane = threadIdx.x & 63, w = threadIdx.x >> 6;
    int wr = w >> 1, wc = w & 1;
    int lrow = lane & 15, rbase = (lane >> 4) * 4;
    int lin = blockIdx.y * 8 + blockIdx.x;
    int lin2 = (lin & 7) * 64 + (lin >> 3);
    int bx = lin2 % 8, by = lin2 / 8;
    int am0 = by * 128;
    int n0 = bx * 128;
    const u16* bmat = wt + ((size_t)3 << 20);

    GEMM_KLOOP(af_in, bmat, am0, n0)

#pragma unroll
    for (int mt = 0; mt < 4; mt++)
#pragma unroll
        for (int nt = 0; nt < 4; nt++) {
            int n = n0 + wc * 64 + nt * 16 + lrow;
            float bias_v = bo[n];
#pragma unroll
            for (int j = 0; j < 4; j++) {
                int m = am0 + wr * 64 + mt * 16 + rbase + j;
                out[(size_t)m * 1024 + n] = acc[mt][nt][j] + bias_v;
            }
        }
}

// ---------------- K2: fused attention (dbuf P-tile, early NT stores) ----------------
// One wg = one (b,h, 16-row Q tile). 8 waves, each owns 256 K-columns.
// Occupancy is register-capped (64V+64A=128 -> 16 waves/CU); LDS up to 80KB is free.
#define NW 8
__global__ __launch_bounds__(512, 4) void k_attn(
    const u16* __restrict__ qf, const u16* __restrict__ kf, const u16* __restrict__ vt,
    float* __restrict__ attn_out, u16* __restrict__ cf) {
    __shared__ float2 sm_ms[NW][16];       // (max, sum) per wave per qrow
    __shared__ float pt[2][NW][16][32];    // f32 P tile, dbuf by c2 parity, slot^=row&7
    __shared__ float ctx_red[NW][16][68];  // full-width single-pass epilogue

    int w = threadIdx.x >> 6, lane = threadIdx.x & 63;
    // XCD-chunked swizzle: 8192 wgs -> 1024/XCD = 8 heads/XCD (K/V L2 reuse)
    int bid0 = blockIdx.x;
    int bid = (bid0 & 7) * 1024 + (bid0 >> 3);
    int qt = bid & 127, bh = bid >> 7;
    int q0 = qt * 16;
    int lrow = lane & 15, rbase = (lane >> 4) * 4;
    int g = lane >> 4;

    const u16* qp  = qf + (size_t)bh * HSZ;
    const u16* kfp = kf + (size_t)bh * HSZ;
    const u16* vtp = vt + (size_t)bh * HSZ;

    // Q as B-operand fragments, fragment-tiled: contiguous per wave
    short8 aq[2];
#pragma unroll
    for (int kk = 0; kk < 2; kk++)
        aq[kk] = *(const short8*)(qp + (size_t)qt * 1024 + kk * 512 + lane * 8);

    f32x4 acc[16];
#pragma unroll
    for (int t = 0; t < 16; t++) acc[t] = (f32x4)0.f;

    int c0w = w * 256;
    int tbase = c0w >> 4;   // K tile base for this wave
    const u16* kl = kfp + (size_t)tbase * 1024 + lane * 8;

    // ---- QK^T: depth-4 K-tile register pipeline (8 loads in flight) ----
    short8 kbuf[4][2];
#pragma unroll
    for (int t = 0; t < 4; t++) {
        kbuf[t][0] = *(const short8*)(kl + (size_t)t * 1024);
        kbuf[t][1] = *(const short8*)(kl + (size_t)t * 1024 + 512);
    }
#pragma unroll
    for (int t = 0; t < 16; t++) {
        short8 b0 = kbuf[t & 3][0];
        short8 b1 = kbuf[t & 3][1];
        if (t < 12) {
            kbuf[t & 3][0] = *(const short8*)(kl + (size_t)(t + 4) * 1024);
            kbuf[t & 3][1] = *(const short8*)(kl + (size_t)(t + 4) * 1024 + 512);
        }
        __builtin_amdgcn_s_setprio(1);
        acc[t] = __builtin_amdgcn_mfma_f32_16x16x32_f16(b0, aq[0], acc[t], 0, 0, 0);
        acc[t] = __builtin_amdgcn_mfma_f32_16x16x32_f16(b1, aq[1], acc[t], 0, 0, 0);
        __builtin_amdgcn_s_setprio(0);
    }

    // ---- V issue-early: first c2-group's loads hide under softmax ----
    int cbase = c0w >> 5;   // V tile base for this wave
    const u16* vl = vtp + (size_t)cbase * 2048 + lane * 8;
    short8 vbuf[2][4];
#pragma unroll
    for (int nt = 0; nt < 4; nt++) vbuf[0][nt] = *(const short8*)(vl + nt * 512);

    // ---- softmax: in-lane reduction + single barrier ----
    float m0_ = acc[0][0], m1_ = acc[0][1], m2_ = acc[0][2], m3_ = acc[0][3];
#pragma unroll
    for (int t = 1; t < 16; t++) {
        m0_ = fmaxf(m0_, acc[t][0]);
        m1_ = fmaxf(m1_, acc[t][1]);
        m2_ = fmaxf(m2_, acc[t][2]);
        m3_ = fmaxf(m3_, acc[t][3]);
    }
    float mv = fmaxf(fmaxf(m0_, m1_), fmaxf(m2_, m3_));
    mv = fmaxf(mv, __shfl_xor(mv, 16, 64));
    mv = fmaxf(mv, __shfl_xor(mv, 32, 64));   // wave-local row max

    const float C = 0.125f * 1.44269504088896f;
    float s0_ = 0.f, s1_ = 0.f, s2_ = 0.f, s3_ = 0.f;
#pragma unroll
    for (int t = 0; t < 16; t++) {
        float e0 = exp2f((acc[t][0] - mv) * C);
        float e1 = exp2f((acc[t][1] - mv) * C);
        float e2 = exp2f((acc[t][2] - mv) * C);
        float e3 = exp2f((acc[t][3] - mv) * C);
        acc[t][0] = e0; acc[t][1] = e1; acc[t][2] = e2; acc[t][3] = e3;
        s0_ += e0; s1_ += e1; s2_ += e2; s3_ += e3;
    }
    float sv = (s0_ + s1_) + (s2_ + s3_);
    sv += __shfl_xor(sv, 16, 64);
    sv += __shfl_xor(sv, 32, 64);             // wave-local row sum

    if (lane < 16) sm_ms[w][lrow] = make_float2(mv, sv);
    __syncthreads();                          // ONE barrier for softmax exchange

    float M = sm_ms[0][lrow].x;
#pragma unroll
    for (int w2 = 1; w2 < NW; w2++) M = fmaxf(M, sm_ms[w2][lrow].x);
    float L = 0.f;
#pragma unroll
    for (int w2 = 0; w2 < NW; w2++) {
        float2 ms = sm_ms[w2][lrow];
        L += ms.y * exp2f((ms.x - M) * C);
    }
    float scale = exp2f((mv - M) * C) / L;

    // ---- PV + early full-line NT stores via dbuf swizzled f32 LDS tile ----
    int srow = lane >> 3, sslot = lane & 7;   // store lane map: 8 rows x 128B lines
    f32x4 cacc[4];
#pragma unroll
    for (int nt = 0; nt < 4; nt++) cacc[nt] = (f32x4)0.f;
#pragma unroll
    for (int c2 = 0; c2 < 8; c2++) {
        int pb = c2 & 1;
        if (c2 < 7) {
#pragma unroll
            for (int nt = 0; nt < 4; nt++)
                vbuf[(c2 + 1) & 1][nt] =
                    *(const short8*)(vl + (size_t)(c2 + 1) * 2048 + nt * 512);
        }
        // scale + stage f32 P[16][32] into swizzled LDS (conflict-free b128)
#pragma unroll
        for (int tt = 0; tt < 2; tt++) {
            int t = c2 * 2 + tt;
            f32x4 pv;
            pv[0] = acc[t][0] * scale; pv[1] = acc[t][1] * scale;
            pv[2] = acc[t][2] * scale; pv[3] = acc[t][3] * scale;
            int sl = (tt * 4 + g) ^ (lrow & 7);
            *(f32x4*)&pt[pb][w][lrow][sl * 4] = pv;
        }
        // full-line NT stores FIRST (enter HBM queue before MFMA crunches)
#pragma unroll
        for (int half = 0; half < 2; half++) {
            int r = half * 8 + srow;
            f32x4 vv = *(const f32x4*)&pt[pb][w][r][(sslot ^ (r & 7)) * 4];
            float* dst = attn_out + ((size_t)bh * SEQ + q0 + r) * SEQ + c0w + c2 * 32 + sslot * 4;
            __builtin_nontemporal_store(vv, (f32x4*)dst);
        }
        // assemble pf (fp16 A-frag: row=qrow, k=kcol) from LDS
        f32x4 plo = *(const f32x4*)&pt[pb][w][lrow][((2 * g) ^ (lrow & 7)) * 4];
        f32x4 phi = *(const f32x4*)&pt[pb][w][lrow][((2 * g + 1) ^ (lrow & 7)) * 4];
        short8 pf;
        u16* pfp = (u16*)&pf;
#pragma unroll
        for (int j = 0; j < 4; j++) {
            pfp[j]     = f32_to_f16(plo[j]);
            pfp[4 + j] = f32_to_f16(phi[j]);
        }
        __builtin_amdgcn_s_setprio(1);
#pragma unroll
        for (int nt = 0; nt < 4; nt++)
            cacc[nt] = __builtin_amdgcn_mfma_f32_16x16x32_f16(pf, vbuf[c2 & 1][nt], cacc[nt], 0, 0, 0);
        __builtin_amdgcn_s_setprio(0);
    }

    // ---- single-pass cross-wave ctx reduce + write ctx fp16 ([B,S,D]) ----
#pragma unroll
    for (int nt = 0; nt < 4; nt++)
#pragma unroll
        for (int j = 0; j < 4; j++)
            ctx_red[w][rbase + j][nt * 16 + lrow] = cacc[nt][j];
    __syncthreads();
    int b = bh >> 4, h = bh & 15;
    int e0 = threadIdx.x * 2;
#pragma unroll
    for (int q = 0; q < 2; q++) {
        int e = e0 + q;
        int r = e >> 6, c = e & 63;
        float s = 0.f;
#pragma unroll
        for (int w2 = 0; w2 < NW; w2++) s += ctx_red[w2][r][c];
        size_t idx = ((size_t)b * SEQ + q0 + r) * DM + h * HD + c;
        cf[idx] = f32_to_f16(s);
    }
}

extern "C" void kernel_launch(void* const* d_in, const int* in_sizes, int n_in,
                              void* d_out, int out_size, void* d_ws, size_t ws_size,
                              hipStream_t stream) {
    const float* x  = (const float*)d_in[0];
    const float* wq = (const float*)d_in[1];
    const float* bq = (const float*)d_in[2];
    const float* wk = (const float*)d_in[3];
    const float* bk = (const float*)d_in[4];
    const float* wv = (const float*)d_in[5];
    const float* bv = (const float*)d_in[6];
    const float* wo = (const float*)d_in[7];
    const float* bo = (const float*)d_in[8];

    float* out  = (float*)d_out;
    float* attn = out + (size_t)BATCH * SEQ * DM;

    char* ws = (char*)d_ws;
    const size_t MB = 1u << 20;
    u16* x16  = (u16*)(ws + 0 * MB);    // 16 MiB
    u16* wt16 = (u16*)(ws + 16 * MB);   // 8 MiB (4 weights, [n][k], fp16)
    u16* qf   = (u16*)(ws + 24 * MB);   // 16 MiB (fragment-tiled)
    u16* kf   = (u16*)(ws + 40 * MB);   // 16 MiB (fragment-tiled)
    u16* vt   = (u16*)(ws + 56 * MB);   // 16 MiB (fragment-tiled)
    u16* cf   = (u16*)(ws + 72 * MB);   // 16 MiB

    int n4 = BATCH * SEQ * DM / 4;
    k_split_x<<<(n4 + 255) / 256, 256, 0, stream>>>((const float4*)x, (ushort4*)x16, n4);
    k_split_w<<<4096, 256, 0, stream>>>(wq, wk, wv, wo, wt16);
    k_gemm_qkv<<<dim3(24, 64), 256, 0, stream>>>(x16, wt16, bq, bk, bv, qf, kf, vt);
    k_attn<<<BATCH * NH * (SEQ / 16), 512, 0, stream>>>(qf, kf, vt, attn, cf);
    k_gemm_out<<<dim3(8, 64), 256, 0, stream>>>(cf, wt16, bo, out);
}